// Round 1
// baseline (549.756 us; speedup 1.0000x reference)
//
#include <hip/hip_runtime.h>

// GCN: N=50000 nodes, E=1.6M edges (+N self-loops), F_IN=11, H=128, G=1024, T=1.
// Pipeline (with layer-3 folded into v3 = W3@Wl, c3 = b3 . Wl):
//   deg/dinv + CSR build -> lin1 = x@W1 -> h1 = relu(agg(lin1)+b1)
//   -> lin2 = h1@W2 -> t[n] = relu(agg(lin2)+b2) . v3   (h2 never materialized)
//   -> s[n] = dinv[n]*sum_e dinv[src]*t[src] + c3 -> segment-mean over batch -> +bl

constexpr int N_NODES = 50000;
constexpr int N_EDGES = 1600000;
constexpr int NE_TOT  = N_EDGES + N_NODES;
constexpr int F_IN_C  = 11;
constexpr int HC      = 128;
constexpr int G_C     = 1024;

// ---------------- graph prep ----------------

__global__ __launch_bounds__(256) void k_hist(const int* __restrict__ dst,
                                              int* __restrict__ deg) {
  int e = blockIdx.x * 256 + threadIdx.x;
  if (e < N_EDGES) atomicAdd(&deg[dst[e]], 1);
}

__global__ __launch_bounds__(256) void k_deg(int* __restrict__ deg,
                                             float* __restrict__ dinv,
                                             int* __restrict__ start,
                                             int* __restrict__ cursor,
                                             int* __restrict__ total) {
  int n = blockIdx.x * 256 + threadIdx.x;
  if (n < N_NODES) {
    int d = deg[n] + 1;              // + self loop
    deg[n] = d;
    dinv[n] = rsqrtf((float)d);      // deg >= 1 always
    int s = atomicAdd(total, d);     // disjoint spans (order irrelevant)
    start[n] = s;
    cursor[n] = s;
  }
}

__global__ __launch_bounds__(256) void k_scatter(const int* __restrict__ src,
                                                 const int* __restrict__ dst,
                                                 int* __restrict__ cursor,
                                                 int* __restrict__ csr) {
  int e = blockIdx.x * 256 + threadIdx.x;
  if (e < NE_TOT) {
    int s, d;
    if (e < N_EDGES) { s = src[e]; d = dst[e]; }
    else             { s = d = e - N_EDGES; }  // self loop
    int pos = atomicAdd(&cursor[d], 1);
    csr[pos] = s;
  }
}

// ---------------- dense pieces ----------------

// lin1 = x @ W1   (N x 11) @ (11 x 128); one node per 128-thread block
__global__ __launch_bounds__(128) void k_lin1(const float* __restrict__ x,
                                              const float* __restrict__ W1,
                                              float* __restrict__ out) {
  int n = blockIdx.x;
  int h = threadIdx.x;
  const float* xr = x + (size_t)n * F_IN_C;
  float acc = 0.f;
#pragma unroll
  for (int k = 0; k < F_IN_C; ++k) acc += xr[k] * W1[k * HC + h];
  out[(size_t)n * HC + h] = acc;
}

// out = in @ W  (H x H). 16 nodes per 128-thread block, LDS-staged inputs.
__global__ __launch_bounds__(128) void k_gemm(const float* __restrict__ in,
                                              const float* __restrict__ W,
                                              float* __restrict__ out) {
  __shared__ float in_s[16][HC];
  int t  = threadIdx.x;
  int n0 = blockIdx.x * 16;
#pragma unroll
  for (int r = 0; r < 16; ++r) in_s[r][t] = in[(size_t)(n0 + r) * HC + t];
  __syncthreads();
  float acc[16];
#pragma unroll
  for (int r = 0; r < 16; ++r) acc[r] = 0.f;
  for (int k = 0; k < HC; ++k) {
    float w = W[k * HC + t];
#pragma unroll
    for (int r = 0; r < 16; ++r) acc[r] += in_s[r][k] * w;  // LDS broadcast
  }
#pragma unroll
  for (int r = 0; r < 16; ++r) out[(size_t)(n0 + r) * HC + t] = acc[r];
}

// v3 = W3 @ Wl (128), c3 = b3 . Wl (scalar). Single 128-thread block.
__global__ __launch_bounds__(128) void k_v3(const float* __restrict__ W3,
                                            const float* __restrict__ b3,
                                            const float* __restrict__ Wl,
                                            float* __restrict__ v3,
                                            float* __restrict__ c3) {
  int k = threadIdx.x;
  float acc = 0.f;
  for (int j = 0; j < HC; ++j) acc += W3[k * HC + j] * Wl[j];
  v3[k] = acc;
  __shared__ float red[128];
  red[k] = b3[k] * Wl[k];
  __syncthreads();
  for (int s = 64; s > 0; s >>= 1) {
    if (k < s) red[k] += red[k + s];
    __syncthreads();
  }
  if (k == 0) *c3 = red[0];
}

// ---------------- sparse aggregation ----------------

// MODE 0: out[n][:] = relu(agg + bias)   (float2 per lane, wave per row)
// MODE 1: out[n]    = relu(agg + bias) . v3   (fused dot, scalar out)
template <int MODE>
__global__ __launch_bounds__(256) void k_spmm(const float* __restrict__ lin,
                                              const float* __restrict__ dinv,
                                              const int* __restrict__ start,
                                              const int* __restrict__ deg,
                                              const int* __restrict__ csr,
                                              const float* __restrict__ bias,
                                              const float* __restrict__ v3,
                                              float* __restrict__ out) {
  int wv = threadIdx.x >> 6, lane = threadIdx.x & 63;
  int n = blockIdx.x * 4 + wv;
  if (n >= N_NODES) return;
  int s0 = start[n], d = deg[n];
  float dn = dinv[n];
  const float2* lp = (const float2*)lin;
  float ax0 = 0.f, ay0 = 0.f, ax1 = 0.f, ay1 = 0.f;
  int i = 0;
  for (; i + 2 <= d; i += 2) {
    int j0 = csr[s0 + i], j1 = csr[s0 + i + 1];
    float w0 = dinv[j0], w1 = dinv[j1];
    float2 v0 = lp[(size_t)j0 * 64 + lane];
    float2 v1 = lp[(size_t)j1 * 64 + lane];
    ax0 += w0 * v0.x; ay0 += w0 * v0.y;
    ax1 += w1 * v1.x; ay1 += w1 * v1.y;
  }
  if (i < d) {
    int j0 = csr[s0 + i];
    float w0 = dinv[j0];
    float2 v0 = lp[(size_t)j0 * 64 + lane];
    ax0 += w0 * v0.x; ay0 += w0 * v0.y;
  }
  float ax = (ax0 + ax1) * dn + bias[lane * 2];
  float ay = (ay0 + ay1) * dn + bias[lane * 2 + 1];
  ax = fmaxf(ax, 0.f);
  ay = fmaxf(ay, 0.f);
  if (MODE == 0) {
    ((float2*)out)[(size_t)n * 64 + lane] = make_float2(ax, ay);
  } else {
    float2 vv = ((const float2*)v3)[lane];
    float p = ax * vv.x + ay * vv.y;
#pragma unroll
    for (int o = 32; o > 0; o >>= 1) p += __shfl_down(p, o, 64);
    if (lane == 0) out[n] = p;
  }
}

// s[n] = dinv[n] * sum_e dinv[src]*t[src] + c3; segment-sum into graphs.
__global__ __launch_bounds__(256) void k_spmv_pool(const float* __restrict__ t,
                                                   const float* __restrict__ dinv,
                                                   const int* __restrict__ start,
                                                   const int* __restrict__ deg,
                                                   const int* __restrict__ csr,
                                                   const float* __restrict__ c3,
                                                   const int* __restrict__ batch,
                                                   float* __restrict__ ssum,
                                                   int* __restrict__ cntg) {
  int n = blockIdx.x * 256 + threadIdx.x;
  if (n >= N_NODES) return;
  int s0 = start[n], d = deg[n];
  float acc = 0.f;
  for (int i = 0; i < d; ++i) {
    int j = csr[s0 + i];
    acc += dinv[j] * t[j];
  }
  acc = acc * dinv[n] + *c3;
  int g = batch[n];
  atomicAdd(&ssum[g], acc);
  atomicAdd(&cntg[g], 1);
}

__global__ __launch_bounds__(256) void k_out(const float* __restrict__ ssum,
                                             const int* __restrict__ cntg,
                                             const float* __restrict__ bl,
                                             float* __restrict__ out) {
  int g = blockIdx.x * 256 + threadIdx.x;
  if (g < G_C) out[g] = ssum[g] / fmaxf((float)cntg[g], 1.f) + bl[0];
}

// ---------------- launch ----------------

extern "C" void kernel_launch(void* const* d_in, const int* in_sizes, int n_in,
                              void* d_out, int out_size, void* d_ws, size_t ws_size,
                              hipStream_t stream) {
  const float* x     = (const float*)d_in[0];
  const int*   ei    = (const int*)d_in[1];
  const int*   srcE  = ei;
  const int*   dstE  = ei + N_EDGES;
  const int*   batch = (const int*)d_in[2];
  const float* W1 = (const float*)d_in[3];
  const float* b1 = (const float*)d_in[4];
  const float* W2 = (const float*)d_in[5];
  const float* b2 = (const float*)d_in[6];
  const float* W3 = (const float*)d_in[7];
  const float* b3 = (const float*)d_in[8];
  const float* Wl = (const float*)d_in[9];
  const float* bl = (const float*)d_in[10];
  float* out = (float*)d_out;

  // workspace layout (16B aligned slices)
  size_t off = 0;
  auto alloc = [&](size_t bytes) -> char* {
    char* p = (char*)d_ws + off;
    off = (off + bytes + 15) & ~(size_t)15;
    return p;
  };
  float* bufA = (float*)alloc((size_t)N_NODES * HC * 4);   // 25.6 MB
  float* bufB = (float*)alloc((size_t)N_NODES * HC * 4);   // 25.6 MB
  float* dinv = (float*)alloc((size_t)N_NODES * 4);
  float* tbuf = (float*)alloc((size_t)N_NODES * 4);
  float* v3   = (float*)alloc(HC * 4);
  float* c3   = (float*)alloc(16);
  int* startA = (int*)alloc((size_t)N_NODES * 4);
  int* cursor = (int*)alloc((size_t)N_NODES * 4);
  int* csr    = (int*)alloc((size_t)NE_TOT * 4);           // 6.6 MB
  // zero zone (single memset): deg | ssum | cntg | total
  size_t zz_bytes = (size_t)N_NODES * 4 + G_C * 4 + G_C * 4 + 16;
  char* zz = alloc(zz_bytes);
  int*   deg  = (int*)zz;
  float* ssum = (float*)(zz + (size_t)N_NODES * 4);
  int*   cntg = (int*)(zz + (size_t)N_NODES * 4 + G_C * 4);
  int*   total= (int*)(zz + (size_t)N_NODES * 4 + G_C * 8);

  hipMemsetAsync(zz, 0, zz_bytes, stream);

  k_hist<<<(N_EDGES + 255) / 256, 256, 0, stream>>>(dstE, deg);
  k_deg<<<(N_NODES + 255) / 256, 256, 0, stream>>>(deg, dinv, startA, cursor, total);
  k_scatter<<<(NE_TOT + 255) / 256, 256, 0, stream>>>(srcE, dstE, cursor, csr);
  k_v3<<<1, 128, 0, stream>>>(W3, b3, Wl, v3, c3);

  k_lin1<<<N_NODES, 128, 0, stream>>>(x, W1, bufA);
  k_spmm<0><<<N_NODES / 4, 256, 0, stream>>>(bufA, dinv, startA, deg, csr, b1, v3, bufB);
  k_gemm<<<N_NODES / 16, 128, 0, stream>>>(bufB, W2, bufA);
  k_spmm<1><<<N_NODES / 4, 256, 0, stream>>>(bufA, dinv, startA, deg, csr, b2, v3, tbuf);
  k_spmv_pool<<<(N_NODES + 255) / 256, 256, 0, stream>>>(tbuf, dinv, startA, deg, csr,
                                                         c3, batch, ssum, cntg);
  k_out<<<(G_C + 255) / 256, 256, 0, stream>>>(ssum, cntg, bl, out);
}

// Round 2
// 522.456 us; speedup vs baseline: 1.0523x; 1.0523x over previous
//
#include <hip/hip_runtime.h>

// GCN: N=50000 nodes, E=1.6M edges (+N self-loops), F_IN=11, H=128, G=1024, T=1.
// Pipeline (layer-3 folded into v3 = W3@Wl, c3 = b3 . Wl):
//   hist(deg) -> deg/prefix/self-loop -> scatter(CSR) ; lin1 = x@W1
//   -> h1 = relu(agg(lin1)+b1) -> lin2 = h1@W2 -> t[n] = relu(agg(lin2)+b2).v3
//   -> s[n] = dinv[n]*sum_e dinv[src]*t[src] + c3 -> segment-mean -> +bl
//
// R2 changes vs R1:
//  * atomic counters padded to 128B/node (32 ints) to break per-cacheline
//    atomic serialization (scatter was 10% HBM BW, 0.4% VALU -> contention).
//    Counter array aliased into bufB (dead until spmm<0>) - ws stays ~58.7MB.
//  * self-loop written in k_deg (scatter handles only real edges).
//  * int4/int2 vectorized edge reads in hist/scatter.
//  * SpMM/SpMV gather loops unrolled x4; lin1 stages W1 in LDS.

constexpr int N_NODES = 50000;
constexpr int N_EDGES = 1600000;
constexpr int F_IN_C  = 11;
constexpr int HC      = 128;
constexpr int G_C     = 1024;
constexpr int PAD     = 32;      // ints per padded counter slot (128 B)

// ---------------- graph prep ----------------

__global__ __launch_bounds__(256) void k_hist(const int* __restrict__ dst,
                                              int* __restrict__ cnt) {
  int e4 = (blockIdx.x * 256 + threadIdx.x) * 4;
  if (e4 < N_EDGES) {
    int4 d = *(const int4*)(dst + e4);
    atomicAdd(&cnt[d.x * PAD], 1);
    atomicAdd(&cnt[d.y * PAD], 1);
    atomicAdd(&cnt[d.z * PAD], 1);
    atomicAdd(&cnt[d.w * PAD], 1);
  }
}

__global__ __launch_bounds__(256) void k_deg(int* __restrict__ cnt,
                                             float* __restrict__ dinv,
                                             int* __restrict__ start,
                                             int* __restrict__ deg,
                                             int* __restrict__ csr,
                                             int* __restrict__ total) {
  int n = blockIdx.x * 256 + threadIdx.x;
  if (n < N_NODES) {
    int d = cnt[n * PAD] + 1;          // + self loop
    deg[n] = d;
    dinv[n] = rsqrtf((float)d);
    int s = atomicAdd(total, d);       // disjoint spans (order irrelevant)
    start[n] = s;
    csr[s] = n;                        // self-loop slot
    cnt[n * PAD] = s + 1;              // cursor for real edges
  }
}

__global__ __launch_bounds__(256) void k_scatter(const int* __restrict__ src,
                                                 const int* __restrict__ dst,
                                                 int* __restrict__ cnt,
                                                 int* __restrict__ csr) {
  int e2 = (blockIdx.x * 256 + threadIdx.x) * 2;
  if (e2 < N_EDGES) {
    int2 s2 = *(const int2*)(src + e2);
    int2 d2 = *(const int2*)(dst + e2);
    int p0 = atomicAdd(&cnt[d2.x * PAD], 1);
    int p1 = atomicAdd(&cnt[d2.y * PAD], 1);
    csr[p0] = s2.x;
    csr[p1] = s2.y;
  }
}

// ---------------- dense pieces ----------------

// lin1 = x @ W1   (N x 11) @ (11 x 128); W1 staged in LDS, grid-stride.
__global__ __launch_bounds__(256) void k_lin1(const float* __restrict__ x,
                                              const float* __restrict__ W1,
                                              float* __restrict__ out) {
  __shared__ float w_s[F_IN_C * HC];
  for (int i = threadIdx.x; i < F_IN_C * HC; i += 256) w_s[i] = W1[i];
  __syncthreads();
  int h    = threadIdx.x & (HC - 1);
  int half = threadIdx.x >> 7;             // 2 nodes per 256-thread block
  for (int n = blockIdx.x * 2 + half; n < N_NODES; n += gridDim.x * 2) {
    const float* xr = x + (size_t)n * F_IN_C;
    float acc = 0.f;
#pragma unroll
    for (int k = 0; k < F_IN_C; ++k) acc += xr[k] * w_s[k * HC + h];
    out[(size_t)n * HC + h] = acc;
  }
}

// out = in @ W  (H x H). 16 nodes per 128-thread block, LDS-staged inputs.
__global__ __launch_bounds__(128) void k_gemm(const float* __restrict__ in,
                                              const float* __restrict__ W,
                                              float* __restrict__ out) {
  __shared__ float in_s[16][HC];
  int t  = threadIdx.x;
  int n0 = blockIdx.x * 16;
#pragma unroll
  for (int r = 0; r < 16; ++r) in_s[r][t] = in[(size_t)(n0 + r) * HC + t];
  __syncthreads();
  float acc[16];
#pragma unroll
  for (int r = 0; r < 16; ++r) acc[r] = 0.f;
  for (int k = 0; k < HC; ++k) {
    float w = W[k * HC + t];
#pragma unroll
    for (int r = 0; r < 16; ++r) acc[r] += in_s[r][k] * w;  // LDS broadcast
  }
#pragma unroll
  for (int r = 0; r < 16; ++r) out[(size_t)(n0 + r) * HC + t] = acc[r];
}

// v3 = W3 @ Wl (128), c3 = b3 . Wl (scalar). Single 128-thread block.
__global__ __launch_bounds__(128) void k_v3(const float* __restrict__ W3,
                                            const float* __restrict__ b3,
                                            const float* __restrict__ Wl,
                                            float* __restrict__ v3,
                                            float* __restrict__ c3) {
  int k = threadIdx.x;
  float acc = 0.f;
  for (int j = 0; j < HC; ++j) acc += W3[k * HC + j] * Wl[j];
  v3[k] = acc;
  __shared__ float red[128];
  red[k] = b3[k] * Wl[k];
  __syncthreads();
  for (int s = 64; s > 0; s >>= 1) {
    if (k < s) red[k] += red[k + s];
    __syncthreads();
  }
  if (k == 0) *c3 = red[0];
}

// ---------------- sparse aggregation ----------------

// MODE 0: out[n][:] = relu(agg + bias)   (float2 per lane, wave per row)
// MODE 1: out[n]    = relu(agg + bias) . v3   (fused dot, scalar out)
template <int MODE>
__global__ __launch_bounds__(256) void k_spmm(const float* __restrict__ lin,
                                              const float* __restrict__ dinv,
                                              const int* __restrict__ start,
                                              const int* __restrict__ deg,
                                              const int* __restrict__ csr,
                                              const float* __restrict__ bias,
                                              const float* __restrict__ v3,
                                              float* __restrict__ out) {
  int wv = threadIdx.x >> 6, lane = threadIdx.x & 63;
  int n = blockIdx.x * 4 + wv;
  if (n >= N_NODES) return;
  int s0 = start[n], d = deg[n];
  float dn = dinv[n];
  const float2* lp = (const float2*)lin;
  float ax0 = 0.f, ay0 = 0.f, ax1 = 0.f, ay1 = 0.f;
  float ax2 = 0.f, ay2 = 0.f, ax3 = 0.f, ay3 = 0.f;
  int i = 0;
  for (; i + 4 <= d; i += 4) {
    int j0 = csr[s0 + i], j1 = csr[s0 + i + 1];
    int j2 = csr[s0 + i + 2], j3 = csr[s0 + i + 3];
    float w0 = dinv[j0], w1 = dinv[j1], w2 = dinv[j2], w3 = dinv[j3];
    float2 v0 = lp[(size_t)j0 * 64 + lane];
    float2 v1 = lp[(size_t)j1 * 64 + lane];
    float2 v2 = lp[(size_t)j2 * 64 + lane];
    float2 v3v = lp[(size_t)j3 * 64 + lane];
    ax0 += w0 * v0.x; ay0 += w0 * v0.y;
    ax1 += w1 * v1.x; ay1 += w1 * v1.y;
    ax2 += w2 * v2.x; ay2 += w2 * v2.y;
    ax3 += w3 * v3v.x; ay3 += w3 * v3v.y;
  }
  for (; i < d; ++i) {
    int j0 = csr[s0 + i];
    float w0 = dinv[j0];
    float2 v0 = lp[(size_t)j0 * 64 + lane];
    ax0 += w0 * v0.x; ay0 += w0 * v0.y;
  }
  float ax = ((ax0 + ax1) + (ax2 + ax3)) * dn + bias[lane * 2];
  float ay = ((ay0 + ay1) + (ay2 + ay3)) * dn + bias[lane * 2 + 1];
  ax = fmaxf(ax, 0.f);
  ay = fmaxf(ay, 0.f);
  if (MODE == 0) {
    ((float2*)out)[(size_t)n * 64 + lane] = make_float2(ax, ay);
  } else {
    float2 vv = ((const float2*)v3)[lane];
    float p = ax * vv.x + ay * vv.y;
#pragma unroll
    for (int o = 32; o > 0; o >>= 1) p += __shfl_down(p, o, 64);
    if (lane == 0) out[n] = p;
  }
}

// s[n] = dinv[n] * sum_e dinv[src]*t[src] + c3; segment-sum into graphs.
__global__ __launch_bounds__(256) void k_spmv_pool(const float* __restrict__ t,
                                                   const float* __restrict__ dinv,
                                                   const int* __restrict__ start,
                                                   const int* __restrict__ deg,
                                                   const int* __restrict__ csr,
                                                   const float* __restrict__ c3,
                                                   const int* __restrict__ batch,
                                                   float* __restrict__ ssum,
                                                   int* __restrict__ cntg) {
  int n = blockIdx.x * 256 + threadIdx.x;
  if (n >= N_NODES) return;
  int s0 = start[n], d = deg[n];
  float a0 = 0.f, a1 = 0.f, a2 = 0.f, a3 = 0.f;
  int i = 0;
  for (; i + 4 <= d; i += 4) {
    int j0 = csr[s0 + i], j1 = csr[s0 + i + 1];
    int j2 = csr[s0 + i + 2], j3 = csr[s0 + i + 3];
    a0 += dinv[j0] * t[j0];
    a1 += dinv[j1] * t[j1];
    a2 += dinv[j2] * t[j2];
    a3 += dinv[j3] * t[j3];
  }
  for (; i < d; ++i) {
    int j0 = csr[s0 + i];
    a0 += dinv[j0] * t[j0];
  }
  float acc = ((a0 + a1) + (a2 + a3)) * dinv[n] + *c3;
  int g = batch[n];
  atomicAdd(&ssum[g], acc);
  atomicAdd(&cntg[g], 1);
}

__global__ __launch_bounds__(256) void k_out(const float* __restrict__ ssum,
                                             const int* __restrict__ cntg,
                                             const float* __restrict__ bl,
                                             float* __restrict__ out) {
  int g = blockIdx.x * 256 + threadIdx.x;
  if (g < G_C) out[g] = ssum[g] / fmaxf((float)cntg[g], 1.f) + bl[0];
}

// ---------------- launch ----------------

extern "C" void kernel_launch(void* const* d_in, const int* in_sizes, int n_in,
                              void* d_out, int out_size, void* d_ws, size_t ws_size,
                              hipStream_t stream) {
  const float* x     = (const float*)d_in[0];
  const int*   ei    = (const int*)d_in[1];
  const int*   srcE  = ei;
  const int*   dstE  = ei + N_EDGES;
  const int*   batch = (const int*)d_in[2];
  const float* W1 = (const float*)d_in[3];
  const float* b1 = (const float*)d_in[4];
  const float* W2 = (const float*)d_in[5];
  const float* b2 = (const float*)d_in[6];
  const float* W3 = (const float*)d_in[7];
  const float* b3 = (const float*)d_in[8];
  const float* Wl = (const float*)d_in[9];
  const float* bl = (const float*)d_in[10];
  float* out = (float*)d_out;

  // workspace layout (16B aligned slices)
  size_t off = 0;
  auto alloc = [&](size_t bytes) -> char* {
    char* p = (char*)d_ws + off;
    off = (off + bytes + 15) & ~(size_t)15;
    return p;
  };
  float* bufA = (float*)alloc((size_t)N_NODES * HC * 4);   // 25.6 MB
  float* bufB = (float*)alloc((size_t)N_NODES * HC * 4);   // 25.6 MB
  // padded counters alias the (currently dead) bufB region: 50000*128B = 6.4MB
  int* cnt = (int*)bufB;
  float* dinv = (float*)alloc((size_t)N_NODES * 4);
  float* tbuf = (float*)alloc((size_t)N_NODES * 4);
  float* v3   = (float*)alloc(HC * 4);
  float* c3   = (float*)alloc(16);
  int* startA = (int*)alloc((size_t)N_NODES * 4);
  int* degA   = (int*)alloc((size_t)N_NODES * 4);
  int* csr    = (int*)alloc((size_t)(N_EDGES + N_NODES) * 4);  // 6.6 MB
  // zero zone: ssum | cntg | total
  size_t zz_bytes = G_C * 4 + G_C * 4 + 16;
  char* zz = alloc(zz_bytes);
  float* ssum = (float*)zz;
  int*   cntg = (int*)(zz + G_C * 4);
  int*   total= (int*)(zz + G_C * 8);

  hipMemsetAsync(cnt, 0, (size_t)N_NODES * PAD * 4, stream);
  hipMemsetAsync(zz, 0, zz_bytes, stream);

  k_hist<<<(N_EDGES / 4 + 255) / 256, 256, 0, stream>>>(dstE, cnt);
  k_deg<<<(N_NODES + 255) / 256, 256, 0, stream>>>(cnt, dinv, startA, degA, csr, total);
  k_scatter<<<(N_EDGES / 2 + 255) / 256, 256, 0, stream>>>(srcE, dstE, cnt, csr);
  k_v3<<<1, 128, 0, stream>>>(W3, b3, Wl, v3, c3);

  k_lin1<<<2048, 256, 0, stream>>>(x, W1, bufA);
  k_spmm<0><<<N_NODES / 4, 256, 0, stream>>>(bufA, dinv, startA, degA, csr, b1, v3, bufB);
  k_gemm<<<N_NODES / 16, 128, 0, stream>>>(bufB, W2, bufA);
  k_spmm<1><<<N_NODES / 4, 256, 0, stream>>>(bufA, dinv, startA, degA, csr, b2, v3, tbuf);
  k_spmv_pool<<<(N_NODES + 255) / 256, 256, 0, stream>>>(tbuf, dinv, startA, degA, csr,
                                                         c3, batch, ssum, cntg);
  k_out<<<(G_C + 255) / 256, 256, 0, stream>>>(ssum, cntg, bl, out);
}

// Round 3
// 367.607 us; speedup vs baseline: 1.4955x; 1.4212x over previous
//
#include <hip/hip_runtime.h>

// GCN: N=50000 nodes, E=1.6M edges (+N self-loops), F_IN=11, H=128, G=1024, T=1.
// Pipeline (layer-3 folded into v3 = W3@Wl, c3 = b3 . Wl):
//   binned counting-sort CSR build (A1 hist -> A2 prefix -> A3 bin -> B build)
//   -> lin1 = x@W1 -> h1 = relu(agg(lin1)+b1) -> lin2 = h1@W2
//   -> t[n] = relu(agg(lin2)+b2).v3 -> s[n]=dinv*sum(dinv*t)+c3 -> mean -> +bl
//
// R3 change: k_hist/k_deg/k_scatter (1.6M random 4B csr writes = 102MB of
// dead-line HBM writebacks, the measured limiter) replaced by a 2-level
// binned counting sort. All fine-grained atomics live in LDS; csr writes land
// in L2-resident per-bucket windows; binned pair records are packed to 32 bits
// (src:16 | dst_local:7). pairs aliases bufA (dead until lin1).

constexpr int N_NODES = 50000;
constexpr int N_EDGES = 1600000;
constexpr int F_IN_C  = 11;
constexpr int HC      = 128;
constexpr int G_C     = 1024;
constexpr int NPB     = 128;                        // nodes per bucket
constexpr int NB      = (N_NODES + NPB - 1) / NPB;  // 391 buckets
constexpr int CHUNK   = 8192;                       // edges per bin block
constexpr int NBLK_E  = (N_EDGES + CHUNK - 1) / CHUNK;

// ---------------- CSR build ----------------

// A1: bucket histogram via per-block LDS counts.
__global__ __launch_bounds__(256) void k_bhist(const int* __restrict__ dst,
                                               int* __restrict__ bcnt) {
  __shared__ int hist[NB];
  int t = threadIdx.x;
  for (int b = t; b < NB; b += 256) hist[b] = 0;
  __syncthreads();
  long e0 = (long)blockIdx.x * CHUNK;
  for (int it = 0; it < CHUNK / 1024; ++it) {
    long e = e0 + it * 1024 + t * 4;
    if (e < N_EDGES) {
      int4 d4 = *(const int4*)(dst + e);
      atomicAdd(&hist[d4.x >> 7], 1);
      atomicAdd(&hist[d4.y >> 7], 1);
      atomicAdd(&hist[d4.z >> 7], 1);
      atomicAdd(&hist[d4.w >> 7], 1);
    }
  }
  __syncthreads();
  for (int b = t; b < NB; b += 256)
    if (hist[b]) atomicAdd(&bcnt[b], hist[b]);
}

// A2: exclusive prefix over bucket counts -> bucket base + cursor.
__global__ __launch_bounds__(512) void k_prefix(const int* __restrict__ bcnt,
                                                int* __restrict__ bbase,
                                                int* __restrict__ bcur) {
  __shared__ int sc[512];
  int t = threadIdx.x;
  int v = (t < NB) ? bcnt[t] : 0;
  sc[t] = v;
  __syncthreads();
  for (int off = 1; off < 512; off <<= 1) {
    int a = (t >= off) ? sc[t - off] : 0;
    __syncthreads();
    sc[t] += a;
    __syncthreads();
  }
  if (t < NB) {
    int excl = sc[t] - v;
    bbase[t] = excl;
    bcur[t]  = excl;
  }
}

// A3: bin edges into bucket regions as packed records (src | dst_local<<16).
__global__ __launch_bounds__(256) void k_bin(const int* __restrict__ src,
                                             const int* __restrict__ dst,
                                             int* __restrict__ bcur,
                                             unsigned int* __restrict__ pairs) {
  __shared__ int hist[NB], base[NB], loff[NB];
  int t = threadIdx.x;
  for (int b = t; b < NB; b += 256) { hist[b] = 0; loff[b] = 0; }
  __syncthreads();
  long e0 = (long)blockIdx.x * CHUNK;
  for (int it = 0; it < CHUNK / 1024; ++it) {
    long e = e0 + it * 1024 + t * 4;
    if (e < N_EDGES) {
      int4 d4 = *(const int4*)(dst + e);
      atomicAdd(&hist[d4.x >> 7], 1);
      atomicAdd(&hist[d4.y >> 7], 1);
      atomicAdd(&hist[d4.z >> 7], 1);
      atomicAdd(&hist[d4.w >> 7], 1);
    }
  }
  __syncthreads();
  for (int b = t; b < NB; b += 256)
    if (hist[b]) base[b] = atomicAdd(&bcur[b], hist[b]);
  __syncthreads();
  for (int it = 0; it < CHUNK / 1024; ++it) {
    long e = e0 + it * 1024 + t * 4;
    if (e < N_EDGES) {
      int4 s4 = *(const int4*)(src + e);
      int4 d4 = *(const int4*)(dst + e);
      {
        int b = d4.x >> 7;
        int l = atomicAdd(&loff[b], 1);
        pairs[base[b] + l] = (unsigned)s4.x | ((unsigned)(d4.x & 127) << 16);
      }
      {
        int b = d4.y >> 7;
        int l = atomicAdd(&loff[b], 1);
        pairs[base[b] + l] = (unsigned)s4.y | ((unsigned)(d4.y & 127) << 16);
      }
      {
        int b = d4.z >> 7;
        int l = atomicAdd(&loff[b], 1);
        pairs[base[b] + l] = (unsigned)s4.z | ((unsigned)(d4.z & 127) << 16);
      }
      {
        int b = d4.w >> 7;
        int l = atomicAdd(&loff[b], 1);
        pairs[base[b] + l] = (unsigned)s4.w | ((unsigned)(d4.w & 127) << 16);
      }
    }
  }
}

// B: per-bucket CSR build. LDS counts/cursors; one global atomic per bucket.
__global__ __launch_bounds__(256) void k_build(const unsigned int* __restrict__ pairs,
                                               const int* __restrict__ bbase,
                                               const int* __restrict__ bcur,
                                               int* __restrict__ total,
                                               int* __restrict__ start,
                                               int* __restrict__ deg,
                                               float* __restrict__ dinv,
                                               int* __restrict__ csr) {
  __shared__ int cntL[NPB], sc[NPB];
  __shared__ int csrBaseL;
  int t = threadIdx.x;
  int b = blockIdx.x;
  int nodeBase = b * NPB;
  int nib = min(NPB, N_NODES - nodeBase);
  int pbase = bbase[b];
  int pend  = bcur[b];         // after A3: base + size
  int size  = pend - pbase;
  if (t < NPB) cntL[t] = 0;
  __syncthreads();
  for (int p = t; p < size; p += 256)
    atomicAdd(&cntL[pairs[pbase + p] >> 16], 1);
  __syncthreads();
  int d = 0;
  if (t < NPB) {
    d = (t < nib) ? cntL[t] + 1 : 0;   // +1 self loop
    sc[t] = d;
  }
  __syncthreads();
  for (int off = 1; off < NPB; off <<= 1) {
    int a = 0;
    if (t < NPB && t >= off) a = sc[t - off];
    __syncthreads();
    if (t < NPB) sc[t] += a;
    __syncthreads();
  }
  if (t == 0) csrBaseL = atomicAdd(total, sc[NPB - 1]);
  __syncthreads();
  int csrBase = csrBaseL;
  if (t < nib) {
    int excl = sc[t] - d;
    int n = nodeBase + t;
    int s = csrBase + excl;
    start[n] = s;
    deg[n]   = d;
    dinv[n]  = rsqrtf((float)d);
    csr[s]   = n;               // self-loop slot
    cntL[t]  = excl + 1;        // local cursor
  }
  __syncthreads();
  for (int p = t; p < size; p += 256) {
    unsigned v = pairs[pbase + p];
    int loc = atomicAdd(&cntL[v >> 16], 1);
    csr[csrBase + loc] = (int)(v & 0xFFFFu);
  }
}

// ---------------- dense pieces ----------------

// lin1 = x @ W1   (N x 11) @ (11 x 128); W1 staged in LDS, grid-stride.
__global__ __launch_bounds__(256) void k_lin1(const float* __restrict__ x,
                                              const float* __restrict__ W1,
                                              float* __restrict__ out) {
  __shared__ float w_s[F_IN_C * HC];
  for (int i = threadIdx.x; i < F_IN_C * HC; i += 256) w_s[i] = W1[i];
  __syncthreads();
  int h    = threadIdx.x & (HC - 1);
  int half = threadIdx.x >> 7;             // 2 nodes per 256-thread block
  for (int n = blockIdx.x * 2 + half; n < N_NODES; n += gridDim.x * 2) {
    const float* xr = x + (size_t)n * F_IN_C;
    float acc = 0.f;
#pragma unroll
    for (int k = 0; k < F_IN_C; ++k) acc += xr[k] * w_s[k * HC + h];
    out[(size_t)n * HC + h] = acc;
  }
}

// out = in @ W  (H x H). 16 nodes per 128-thread block, LDS-staged inputs.
__global__ __launch_bounds__(128) void k_gemm(const float* __restrict__ in,
                                              const float* __restrict__ W,
                                              float* __restrict__ out) {
  __shared__ float in_s[16][HC];
  int t  = threadIdx.x;
  int n0 = blockIdx.x * 16;
#pragma unroll
  for (int r = 0; r < 16; ++r) in_s[r][t] = in[(size_t)(n0 + r) * HC + t];
  __syncthreads();
  float acc[16];
#pragma unroll
  for (int r = 0; r < 16; ++r) acc[r] = 0.f;
  for (int k = 0; k < HC; ++k) {
    float w = W[k * HC + t];
#pragma unroll
    for (int r = 0; r < 16; ++r) acc[r] += in_s[r][k] * w;  // LDS broadcast
  }
#pragma unroll
  for (int r = 0; r < 16; ++r) out[(size_t)(n0 + r) * HC + t] = acc[r];
}

// v3 = W3 @ Wl (128), c3 = b3 . Wl (scalar). Single 128-thread block.
__global__ __launch_bounds__(128) void k_v3(const float* __restrict__ W3,
                                            const float* __restrict__ b3,
                                            const float* __restrict__ Wl,
                                            float* __restrict__ v3,
                                            float* __restrict__ c3) {
  int k = threadIdx.x;
  float acc = 0.f;
  for (int j = 0; j < HC; ++j) acc += W3[k * HC + j] * Wl[j];
  v3[k] = acc;
  __shared__ float red[128];
  red[k] = b3[k] * Wl[k];
  __syncthreads();
  for (int s = 64; s > 0; s >>= 1) {
    if (k < s) red[k] += red[k + s];
    __syncthreads();
  }
  if (k == 0) *c3 = red[0];
}

// ---------------- sparse aggregation ----------------

// MODE 0: out[n][:] = relu(agg + bias)   (float2 per lane, wave per row)
// MODE 1: out[n]    = relu(agg + bias) . v3   (fused dot, scalar out)
template <int MODE>
__global__ __launch_bounds__(256) void k_spmm(const float* __restrict__ lin,
                                              const float* __restrict__ dinv,
                                              const int* __restrict__ start,
                                              const int* __restrict__ deg,
                                              const int* __restrict__ csr,
                                              const float* __restrict__ bias,
                                              const float* __restrict__ v3,
                                              float* __restrict__ out) {
  int wv = threadIdx.x >> 6, lane = threadIdx.x & 63;
  int n = blockIdx.x * 4 + wv;
  if (n >= N_NODES) return;
  int s0 = start[n], d = deg[n];
  float dn = dinv[n];
  const float2* lp = (const float2*)lin;
  float ax0 = 0.f, ay0 = 0.f, ax1 = 0.f, ay1 = 0.f;
  float ax2 = 0.f, ay2 = 0.f, ax3 = 0.f, ay3 = 0.f;
  int i = 0;
  for (; i + 4 <= d; i += 4) {
    int j0 = csr[s0 + i], j1 = csr[s0 + i + 1];
    int j2 = csr[s0 + i + 2], j3 = csr[s0 + i + 3];
    float w0 = dinv[j0], w1 = dinv[j1], w2 = dinv[j2], w3 = dinv[j3];
    float2 v0 = lp[(size_t)j0 * 64 + lane];
    float2 v1 = lp[(size_t)j1 * 64 + lane];
    float2 v2 = lp[(size_t)j2 * 64 + lane];
    float2 v3v = lp[(size_t)j3 * 64 + lane];
    ax0 += w0 * v0.x; ay0 += w0 * v0.y;
    ax1 += w1 * v1.x; ay1 += w1 * v1.y;
    ax2 += w2 * v2.x; ay2 += w2 * v2.y;
    ax3 += w3 * v3v.x; ay3 += w3 * v3v.y;
  }
  for (; i < d; ++i) {
    int j0 = csr[s0 + i];
    float w0 = dinv[j0];
    float2 v0 = lp[(size_t)j0 * 64 + lane];
    ax0 += w0 * v0.x; ay0 += w0 * v0.y;
  }
  float ax = ((ax0 + ax1) + (ax2 + ax3)) * dn + bias[lane * 2];
  float ay = ((ay0 + ay1) + (ay2 + ay3)) * dn + bias[lane * 2 + 1];
  ax = fmaxf(ax, 0.f);
  ay = fmaxf(ay, 0.f);
  if (MODE == 0) {
    ((float2*)out)[(size_t)n * 64 + lane] = make_float2(ax, ay);
  } else {
    float2 vv = ((const float2*)v3)[lane];
    float p = ax * vv.x + ay * vv.y;
#pragma unroll
    for (int o = 32; o > 0; o >>= 1) p += __shfl_down(p, o, 64);
    if (lane == 0) out[n] = p;
  }
}

// s[n] = dinv[n] * sum_e dinv[src]*t[src] + c3; segment-sum into graphs.
__global__ __launch_bounds__(256) void k_spmv_pool(const float* __restrict__ t,
                                                   const float* __restrict__ dinv,
                                                   const int* __restrict__ start,
                                                   const int* __restrict__ deg,
                                                   const int* __restrict__ csr,
                                                   const float* __restrict__ c3,
                                                   const int* __restrict__ batch,
                                                   float* __restrict__ ssum,
                                                   int* __restrict__ cntg) {
  int n = blockIdx.x * 256 + threadIdx.x;
  if (n >= N_NODES) return;
  int s0 = start[n], d = deg[n];
  float a0 = 0.f, a1 = 0.f, a2 = 0.f, a3 = 0.f;
  int i = 0;
  for (; i + 4 <= d; i += 4) {
    int j0 = csr[s0 + i], j1 = csr[s0 + i + 1];
    int j2 = csr[s0 + i + 2], j3 = csr[s0 + i + 3];
    a0 += dinv[j0] * t[j0];
    a1 += dinv[j1] * t[j1];
    a2 += dinv[j2] * t[j2];
    a3 += dinv[j3] * t[j3];
  }
  for (; i < d; ++i) {
    int j0 = csr[s0 + i];
    a0 += dinv[j0] * t[j0];
  }
  float acc = ((a0 + a1) + (a2 + a3)) * dinv[n] + *c3;
  int g = batch[n];
  atomicAdd(&ssum[g], acc);
  atomicAdd(&cntg[g], 1);
}

__global__ __launch_bounds__(256) void k_out(const float* __restrict__ ssum,
                                             const int* __restrict__ cntg,
                                             const float* __restrict__ bl,
                                             float* __restrict__ out) {
  int g = blockIdx.x * 256 + threadIdx.x;
  if (g < G_C) out[g] = ssum[g] / fmaxf((float)cntg[g], 1.f) + bl[0];
}

// ---------------- launch ----------------

extern "C" void kernel_launch(void* const* d_in, const int* in_sizes, int n_in,
                              void* d_out, int out_size, void* d_ws, size_t ws_size,
                              hipStream_t stream) {
  const float* x     = (const float*)d_in[0];
  const int*   ei    = (const int*)d_in[1];
  const int*   srcE  = ei;
  const int*   dstE  = ei + N_EDGES;
  const int*   batch = (const int*)d_in[2];
  const float* W1 = (const float*)d_in[3];
  const float* b1 = (const float*)d_in[4];
  const float* W2 = (const float*)d_in[5];
  const float* b2 = (const float*)d_in[6];
  const float* W3 = (const float*)d_in[7];
  const float* b3 = (const float*)d_in[8];
  const float* Wl = (const float*)d_in[9];
  const float* bl = (const float*)d_in[10];
  float* out = (float*)d_out;

  // workspace layout (16B aligned slices)
  size_t off = 0;
  auto alloc = [&](size_t bytes) -> char* {
    char* p = (char*)d_ws + off;
    off = (off + bytes + 15) & ~(size_t)15;
    return p;
  };
  float* bufA = (float*)alloc((size_t)N_NODES * HC * 4);   // 25.6 MB
  float* bufB = (float*)alloc((size_t)N_NODES * HC * 4);   // 25.6 MB
  unsigned int* pairs = (unsigned int*)bufA;               // dead until lin1
  float* dinv = (float*)alloc((size_t)N_NODES * 4);
  float* tbuf = (float*)alloc((size_t)N_NODES * 4);
  float* v3   = (float*)alloc(HC * 4);
  float* c3   = (float*)alloc(16);
  int* startA = (int*)alloc((size_t)N_NODES * 4);
  int* degA   = (int*)alloc((size_t)N_NODES * 4);
  int* csr    = (int*)alloc((size_t)(N_EDGES + N_NODES) * 4);  // 6.6 MB
  int* bbase  = (int*)alloc(NB * 4);
  int* bcur   = (int*)alloc(NB * 4);
  // zero zone: bcnt | total | ssum | cntg
  size_t zz_bytes = NB * 4 + 16 + G_C * 4 + G_C * 4;
  char* zz = alloc(zz_bytes);
  int*   bcnt = (int*)zz;
  int*   total= (int*)(zz + NB * 4);
  float* ssum = (float*)(zz + NB * 4 + 16);
  int*   cntg = (int*)(zz + NB * 4 + 16 + G_C * 4);

  hipMemsetAsync(zz, 0, zz_bytes, stream);

  k_bhist<<<NBLK_E, 256, 0, stream>>>(dstE, bcnt);
  k_prefix<<<1, 512, 0, stream>>>(bcnt, bbase, bcur);
  k_bin<<<NBLK_E, 256, 0, stream>>>(srcE, dstE, bcur, pairs);
  k_build<<<NB, 256, 0, stream>>>(pairs, bbase, bcur, total, startA, degA, dinv, csr);
  k_v3<<<1, 128, 0, stream>>>(W3, b3, Wl, v3, c3);

  k_lin1<<<2048, 256, 0, stream>>>(x, W1, bufA);
  k_spmm<0><<<N_NODES / 4, 256, 0, stream>>>(bufA, dinv, startA, degA, csr, b1, v3, bufB);
  k_gemm<<<N_NODES / 16, 128, 0, stream>>>(bufB, W2, bufA);
  k_spmm<1><<<N_NODES / 4, 256, 0, stream>>>(bufA, dinv, startA, degA, csr, b2, v3, tbuf);
  k_spmv_pool<<<(N_NODES + 255) / 256, 256, 0, stream>>>(tbuf, dinv, startA, degA, csr,
                                                         c3, batch, ssum, cntg);
  k_out<<<(G_C + 255) / 256, 256, 0, stream>>>(ssum, cntg, bl, out);
}

// Round 6
// 275.643 us; speedup vs baseline: 1.9944x; 1.3336x over previous
//
#include <hip/hip_runtime.h>
#include <hip/hip_fp16.h>

// GCN: N=50000 nodes, E=1.6M edges (+N self-loops), F_IN=11, H=128, G=1024, T=1.
// Pipeline (layer-3 folded into v3 = W3@Wl, c3 = b3 . Wl):
//   binned counting-sort CSR build (A1 hist -> A2 prefix -> A3 bin -> B build)
//   -> lin1 = x@W1 (fp16) -> h1 = relu(agg(lin1)+b1) (fp32)
//   -> lin2 = h1@W2 (fp16) -> t[n] = relu(agg(lin2)+b2).v3
//   -> s[n] = dinv*sum(dinv*t)+c3 -> segment-mean -> +bl
//
// R6 change: R4/R5 failures were NOT precision (fp16 ulp 8x smaller than bf16
// gave the SAME ~3e-3 error) but a k_gemm bug from the R4 packing rewrite:
// threads t>=64 read W[k*HC+2t] out of row bounds AND wrote into the next
// node's packed row (write race). Fixed: 64 column-pairs x 2 row-groups.
// fp16 storage kept (predicted intrinsic error ~1e-4 << 6.45e-4 threshold).

constexpr int N_NODES = 50000;
constexpr int N_EDGES = 1600000;
constexpr int F_IN_C  = 11;
constexpr int HC      = 128;
constexpr int G_C     = 1024;
constexpr int NPB     = 128;                        // nodes per bucket
constexpr int NB      = (N_NODES + NPB - 1) / NPB;  // 391 buckets
constexpr int CHUNK   = 8192;                       // edges per bin block
constexpr int NBLK_E  = (N_EDGES + CHUNK - 1) / CHUNK;

// ---------------- fp16 pack/unpack ----------------

__device__ __forceinline__ unsigned pack_f16(float x, float y) {
  __half2 h = __floats2half2_rn(x, y);
  return *reinterpret_cast<unsigned*>(&h);
}

__device__ __forceinline__ float2 unpack_f16(unsigned u) {
  __half2 h = *reinterpret_cast<__half2*>(&u);
  return __half22float2(h);
}

// ---------------- CSR build ----------------

// A1: bucket histogram via per-block LDS counts.
__global__ __launch_bounds__(256) void k_bhist(const int* __restrict__ dst,
                                               int* __restrict__ bcnt) {
  __shared__ int hist[NB];
  int t = threadIdx.x;
  for (int b = t; b < NB; b += 256) hist[b] = 0;
  __syncthreads();
  long e0 = (long)blockIdx.x * CHUNK;
  for (int it = 0; it < CHUNK / 1024; ++it) {
    long e = e0 + it * 1024 + t * 4;
    if (e < N_EDGES) {
      int4 d4 = *(const int4*)(dst + e);
      atomicAdd(&hist[d4.x >> 7], 1);
      atomicAdd(&hist[d4.y >> 7], 1);
      atomicAdd(&hist[d4.z >> 7], 1);
      atomicAdd(&hist[d4.w >> 7], 1);
    }
  }
  __syncthreads();
  for (int b = t; b < NB; b += 256)
    if (hist[b]) atomicAdd(&bcnt[b], hist[b]);
}

// A2: exclusive prefix over bucket counts -> bucket base + cursor.
__global__ __launch_bounds__(512) void k_prefix(const int* __restrict__ bcnt,
                                                int* __restrict__ bbase,
                                                int* __restrict__ bcur) {
  __shared__ int sc[512];
  int t = threadIdx.x;
  int v = (t < NB) ? bcnt[t] : 0;
  sc[t] = v;
  __syncthreads();
  for (int off = 1; off < 512; off <<= 1) {
    int a = (t >= off) ? sc[t - off] : 0;
    __syncthreads();
    sc[t] += a;
    __syncthreads();
  }
  if (t < NB) {
    int excl = sc[t] - v;
    bbase[t] = excl;
    bcur[t]  = excl;
  }
}

// A3: bin edges into bucket regions as packed records (src | dst_local<<16).
__global__ __launch_bounds__(256) void k_bin(const int* __restrict__ src,
                                             const int* __restrict__ dst,
                                             int* __restrict__ bcur,
                                             unsigned int* __restrict__ pairs) {
  __shared__ int hist[NB], base[NB], loff[NB];
  int t = threadIdx.x;
  for (int b = t; b < NB; b += 256) { hist[b] = 0; loff[b] = 0; }
  __syncthreads();
  long e0 = (long)blockIdx.x * CHUNK;
  for (int it = 0; it < CHUNK / 1024; ++it) {
    long e = e0 + it * 1024 + t * 4;
    if (e < N_EDGES) {
      int4 d4 = *(const int4*)(dst + e);
      atomicAdd(&hist[d4.x >> 7], 1);
      atomicAdd(&hist[d4.y >> 7], 1);
      atomicAdd(&hist[d4.z >> 7], 1);
      atomicAdd(&hist[d4.w >> 7], 1);
    }
  }
  __syncthreads();
  for (int b = t; b < NB; b += 256)
    if (hist[b]) base[b] = atomicAdd(&bcur[b], hist[b]);
  __syncthreads();
  for (int it = 0; it < CHUNK / 1024; ++it) {
    long e = e0 + it * 1024 + t * 4;
    if (e < N_EDGES) {
      int4 s4 = *(const int4*)(src + e);
      int4 d4 = *(const int4*)(dst + e);
      {
        int b = d4.x >> 7;
        int l = atomicAdd(&loff[b], 1);
        pairs[base[b] + l] = (unsigned)s4.x | ((unsigned)(d4.x & 127) << 16);
      }
      {
        int b = d4.y >> 7;
        int l = atomicAdd(&loff[b], 1);
        pairs[base[b] + l] = (unsigned)s4.y | ((unsigned)(d4.y & 127) << 16);
      }
      {
        int b = d4.z >> 7;
        int l = atomicAdd(&loff[b], 1);
        pairs[base[b] + l] = (unsigned)s4.z | ((unsigned)(d4.z & 127) << 16);
      }
      {
        int b = d4.w >> 7;
        int l = atomicAdd(&loff[b], 1);
        pairs[base[b] + l] = (unsigned)s4.w | ((unsigned)(d4.w & 127) << 16);
      }
    }
  }
}

// B: per-bucket CSR build. LDS counts/cursors; one global atomic per bucket.
__global__ __launch_bounds__(256) void k_build(const unsigned int* __restrict__ pairs,
                                               const int* __restrict__ bbase,
                                               const int* __restrict__ bcur,
                                               int* __restrict__ total,
                                               int* __restrict__ start,
                                               int* __restrict__ deg,
                                               float* __restrict__ dinv,
                                               int* __restrict__ csr) {
  __shared__ int cntL[NPB], sc[NPB];
  __shared__ int csrBaseL;
  int t = threadIdx.x;
  int b = blockIdx.x;
  int nodeBase = b * NPB;
  int nib = min(NPB, N_NODES - nodeBase);
  int pbase = bbase[b];
  int pend  = bcur[b];         // after A3: base + size
  int size  = pend - pbase;
  if (t < NPB) cntL[t] = 0;
  __syncthreads();
  for (int p = t; p < size; p += 256)
    atomicAdd(&cntL[pairs[pbase + p] >> 16], 1);
  __syncthreads();
  int d = 0;
  if (t < NPB) {
    d = (t < nib) ? cntL[t] + 1 : 0;   // +1 self loop
    sc[t] = d;
  }
  __syncthreads();
  for (int off = 1; off < NPB; off <<= 1) {
    int a = 0;
    if (t < NPB && t >= off) a = sc[t - off];
    __syncthreads();
    if (t < NPB) sc[t] += a;
    __syncthreads();
  }
  if (t == 0) csrBaseL = atomicAdd(total, sc[NPB - 1]);
  __syncthreads();
  int csrBase = csrBaseL;
  if (t < nib) {
    int excl = sc[t] - d;
    int n = nodeBase + t;
    int s = csrBase + excl;
    start[n] = s;
    deg[n]   = d;
    dinv[n]  = rsqrtf((float)d);
    csr[s]   = n;               // self-loop slot
    cntL[t]  = excl + 1;        // local cursor
  }
  __syncthreads();
  for (int p = t; p < size; p += 256) {
    unsigned v = pairs[pbase + p];
    int loc = atomicAdd(&cntL[v >> 16], 1);
    csr[csrBase + loc] = (int)(v & 0xFFFFu);
  }
}

// ---------------- dense pieces ----------------

// lin1 = x @ W1, output packed fp16. 4 nodes per 256-thread block.
__global__ __launch_bounds__(256) void k_lin1(const float* __restrict__ x,
                                              const float* __restrict__ W1,
                                              unsigned* __restrict__ out) {
  __shared__ float w_s[F_IN_C * HC];
  for (int i = threadIdx.x; i < F_IN_C * HC; i += 256) w_s[i] = W1[i];
  __syncthreads();
  int lane = threadIdx.x & 63;
  int sub  = threadIdx.x >> 6;            // 4 nodes per block
  for (int n = blockIdx.x * 4 + sub; n < N_NODES; n += gridDim.x * 4) {
    const float* xr = x + (size_t)n * F_IN_C;
    float ax = 0.f, ay = 0.f;
#pragma unroll
    for (int k = 0; k < F_IN_C; ++k) {
      float xv = xr[k];
      ax += xv * w_s[k * HC + 2 * lane];
      ay += xv * w_s[k * HC + 2 * lane + 1];
    }
    out[(size_t)n * 64 + lane] = pack_f16(ax, ay);
  }
}

// lin2 = h1 @ W2 (fp32 in, packed fp16 out). 16 nodes per 128-thread block.
// Thread t: column pair tp = t&63 (cols 2tp, 2tp+1), row group rg = t>>6
// (rows rg*8 .. rg*8+7). No OOB W reads, no overlapping writes (R4 bug fix).
__global__ __launch_bounds__(128) void k_gemm(const float* __restrict__ in,
                                              const float* __restrict__ W,
                                              unsigned* __restrict__ out) {
  __shared__ float in_s[16][HC];
  int t  = threadIdx.x;
  int n0 = blockIdx.x * 16;
#pragma unroll
  for (int r = 0; r < 16; ++r) in_s[r][t] = in[(size_t)(n0 + r) * HC + t];
  __syncthreads();
  int tp = t & 63;
  int rg = t >> 6;
  float accx[8], accy[8];
#pragma unroll
  for (int r = 0; r < 8; ++r) { accx[r] = 0.f; accy[r] = 0.f; }
  for (int k = 0; k < HC; ++k) {
    float2 w2 = *(const float2*)(W + k * HC + 2 * tp);
#pragma unroll
    for (int r = 0; r < 8; ++r) {
      float a = in_s[rg * 8 + r][k];        // wave-uniform LDS broadcast
      accx[r] += a * w2.x;
      accy[r] += a * w2.y;
    }
  }
#pragma unroll
  for (int r = 0; r < 8; ++r)
    out[(size_t)(n0 + rg * 8 + r) * 64 + tp] = pack_f16(accx[r], accy[r]);
}

// v3 = W3 @ Wl (128), c3 = b3 . Wl (scalar). Single 128-thread block.
__global__ __launch_bounds__(128) void k_v3(const float* __restrict__ W3,
                                            const float* __restrict__ b3,
                                            const float* __restrict__ Wl,
                                            float* __restrict__ v3,
                                            float* __restrict__ c3) {
  int k = threadIdx.x;
  float acc = 0.f;
  for (int j = 0; j < HC; ++j) acc += W3[k * HC + j] * Wl[j];
  v3[k] = acc;
  __shared__ float red[128];
  red[k] = b3[k] * Wl[k];
  __syncthreads();
  for (int s = 64; s > 0; s >>= 1) {
    if (k < s) red[k] += red[k + s];
    __syncthreads();
  }
  if (k == 0) *c3 = red[0];
}

// ---------------- sparse aggregation ----------------

// Gathers packed-fp16 rows (256B = 64 lanes x 1 dword), accumulates fp32.
// MODE 0: out[n][:] = relu(agg + bias)   (float2 per lane, fp32 out)
// MODE 1: out[n]    = relu(agg + bias) . v3   (fused dot, scalar out)
template <int MODE>
__global__ __launch_bounds__(256) void k_spmm(const unsigned* __restrict__ lin,
                                              const float* __restrict__ dinv,
                                              const int* __restrict__ start,
                                              const int* __restrict__ deg,
                                              const int* __restrict__ csr,
                                              const float* __restrict__ bias,
                                              const float* __restrict__ v3,
                                              float* __restrict__ out) {
  int wv = threadIdx.x >> 6, lane = threadIdx.x & 63;
  int n = blockIdx.x * 4 + wv;
  if (n >= N_NODES) return;
  int s0 = start[n], d = deg[n];
  float dn = dinv[n];
  float ax[8], ay[8];
#pragma unroll
  for (int u = 0; u < 8; ++u) { ax[u] = 0.f; ay[u] = 0.f; }
  int i = 0;
  for (; i + 8 <= d; i += 8) {
    int j[8];
    float w[8];
    unsigned q[8];
#pragma unroll
    for (int u = 0; u < 8; ++u) j[u] = csr[s0 + i + u];
#pragma unroll
    for (int u = 0; u < 8; ++u) w[u] = dinv[j[u]];
#pragma unroll
    for (int u = 0; u < 8; ++u) q[u] = lin[(size_t)j[u] * 64 + lane];
#pragma unroll
    for (int u = 0; u < 8; ++u) {
      float2 v = unpack_f16(q[u]);
      ax[u] += w[u] * v.x;
      ay[u] += w[u] * v.y;
    }
  }
  for (; i < d; ++i) {
    int j0 = csr[s0 + i];
    float w0 = dinv[j0];
    float2 v = unpack_f16(lin[(size_t)j0 * 64 + lane]);
    ax[0] += w0 * v.x;
    ay[0] += w0 * v.y;
  }
  float sx = ((ax[0] + ax[1]) + (ax[2] + ax[3])) + ((ax[4] + ax[5]) + (ax[6] + ax[7]));
  float sy = ((ay[0] + ay[1]) + (ay[2] + ay[3])) + ((ay[4] + ay[5]) + (ay[6] + ay[7]));
  sx = fmaxf(sx * dn + bias[lane * 2], 0.f);
  sy = fmaxf(sy * dn + bias[lane * 2 + 1], 0.f);
  if (MODE == 0) {
    ((float2*)out)[(size_t)n * 64 + lane] = make_float2(sx, sy);
  } else {
    float2 vv = ((const float2*)v3)[lane];
    float p = sx * vv.x + sy * vv.y;
#pragma unroll
    for (int o = 32; o > 0; o >>= 1) p += __shfl_down(p, o, 64);
    if (lane == 0) out[n] = p;
  }
}

// s[n] = dinv[n] * sum_e dinv[src]*t[src] + c3; segment-sum into graphs.
__global__ __launch_bounds__(256) void k_spmv_pool(const float* __restrict__ t,
                                                   const float* __restrict__ dinv,
                                                   const int* __restrict__ start,
                                                   const int* __restrict__ deg,
                                                   const int* __restrict__ csr,
                                                   const float* __restrict__ c3,
                                                   const int* __restrict__ batch,
                                                   float* __restrict__ ssum,
                                                   int* __restrict__ cntg) {
  int n = blockIdx.x * 256 + threadIdx.x;
  if (n >= N_NODES) return;
  int s0 = start[n], d = deg[n];
  float a0 = 0.f, a1 = 0.f, a2 = 0.f, a3 = 0.f;
  int i = 0;
  for (; i + 4 <= d; i += 4) {
    int j0 = csr[s0 + i], j1 = csr[s0 + i + 1];
    int j2 = csr[s0 + i + 2], j3 = csr[s0 + i + 3];
    a0 += dinv[j0] * t[j0];
    a1 += dinv[j1] * t[j1];
    a2 += dinv[j2] * t[j2];
    a3 += dinv[j3] * t[j3];
  }
  for (; i < d; ++i) {
    int j0 = csr[s0 + i];
    a0 += dinv[j0] * t[j0];
  }
  float acc = ((a0 + a1) + (a2 + a3)) * dinv[n] + *c3;
  int g = batch[n];
  atomicAdd(&ssum[g], acc);
  atomicAdd(&cntg[g], 1);
}

__global__ __launch_bounds__(256) void k_out(const float* __restrict__ ssum,
                                             const int* __restrict__ cntg,
                                             const float* __restrict__ bl,
                                             float* __restrict__ out) {
  int g = blockIdx.x * 256 + threadIdx.x;
  if (g < G_C) out[g] = ssum[g] / fmaxf((float)cntg[g], 1.f) + bl[0];
}

// ---------------- launch ----------------

extern "C" void kernel_launch(void* const* d_in, const int* in_sizes, int n_in,
                              void* d_out, int out_size, void* d_ws, size_t ws_size,
                              hipStream_t stream) {
  const float* x     = (const float*)d_in[0];
  const int*   ei    = (const int*)d_in[1];
  const int*   srcE  = ei;
  const int*   dstE  = ei + N_EDGES;
  const int*   batch = (const int*)d_in[2];
  const float* W1 = (const float*)d_in[3];
  const float* b1 = (const float*)d_in[4];
  const float* W2 = (const float*)d_in[5];
  const float* b2 = (const float*)d_in[6];
  const float* W3 = (const float*)d_in[7];
  const float* b3 = (const float*)d_in[8];
  const float* Wl = (const float*)d_in[9];
  const float* bl = (const float*)d_in[10];
  float* out = (float*)d_out;

  // workspace layout (16B aligned slices)
  size_t off = 0;
  auto alloc = [&](size_t bytes) -> char* {
    char* p = (char*)d_ws + off;
    off = (off + bytes + 15) & ~(size_t)15;
    return p;
  };
  // bufA: pairs (6.4MB, CSR build) -> lin1 fp16 (12.8MB, lo) + lin2 fp16 (12.8MB, hi)
  char* bufA = alloc((size_t)N_NODES * HC * 4);            // 25.6 MB
  float* bufB = (float*)alloc((size_t)N_NODES * HC * 4);   // 25.6 MB (h1 fp32)
  unsigned* pairs = (unsigned*)bufA;
  unsigned* lin1  = (unsigned*)bufA;                       // 50000*64 uints
  unsigned* lin2  = (unsigned*)(bufA + (size_t)N_NODES * 64 * 4);
  float* dinv = (float*)alloc((size_t)N_NODES * 4);
  float* tbuf = (float*)alloc((size_t)N_NODES * 4);
  float* v3   = (float*)alloc(HC * 4);
  float* c3   = (float*)alloc(16);
  int* startA = (int*)alloc((size_t)N_NODES * 4);
  int* degA   = (int*)alloc((size_t)N_NODES * 4);
  int* csr    = (int*)alloc((size_t)(N_EDGES + N_NODES) * 4);  // 6.6 MB
  int* bbase  = (int*)alloc(NB * 4);
  int* bcur   = (int*)alloc(NB * 4);
  // zero zone: bcnt | total | ssum | cntg
  size_t zz_bytes = NB * 4 + 16 + G_C * 4 + G_C * 4;
  char* zz = alloc(zz_bytes);
  int*   bcnt = (int*)zz;
  int*   total= (int*)(zz + NB * 4);
  float* ssum = (float*)(zz + NB * 4 + 16);
  int*   cntg = (int*)(zz + NB * 4 + 16 + G_C * 4);

  hipMemsetAsync(zz, 0, zz_bytes, stream);

  k_bhist<<<NBLK_E, 256, 0, stream>>>(dstE, bcnt);
  k_prefix<<<1, 512, 0, stream>>>(bcnt, bbase, bcur);
  k_bin<<<NBLK_E, 256, 0, stream>>>(srcE, dstE, bcur, pairs);
  k_build<<<NB, 256, 0, stream>>>(pairs, bbase, bcur, total, startA, degA, dinv, csr);
  k_v3<<<1, 128, 0, stream>>>(W3, b3, Wl, v3, c3);

  k_lin1<<<N_NODES / 4, 256, 0, stream>>>(x, W1, lin1);
  k_spmm<0><<<N_NODES / 4, 256, 0, stream>>>(lin1, dinv, startA, degA, csr, b1, v3, bufB);
  k_gemm<<<N_NODES / 16, 128, 0, stream>>>(bufB, W2, lin2);
  k_spmm<1><<<N_NODES / 4, 256, 0, stream>>>(lin2, dinv, startA, degA, csr, b2, v3, tbuf);
  k_spmv_pool<<<(N_NODES + 255) / 256, 256, 0, stream>>>(tbuf, dinv, startA, degA, csr,
                                                         c3, batch, ssum, cntg);
  k_out<<<(G_C + 255) / 256, 256, 0, stream>>>(ssum, cntg, bl, out);
}

// Round 7
// 245.133 us; speedup vs baseline: 2.2427x; 1.1245x over previous
//
#include <hip/hip_runtime.h>
#include <hip/hip_fp16.h>

// GCN: N=50000 nodes, E=1.6M edges (+N self-loops), F_IN=11, H=128, G=1024, T=1.
// Pipeline (layer-3 folded into v3 = W3@Wl, c3 = b3 . Wl):
//   binned counting-sort CSR build (A1 hist -> A2 prefix -> A3 bin -> B build)
//   -> lin1' = dinv*(x@W1) (fp16) -> h1 = relu(dinv*agg(lin1')+b1) (fp32)
//   -> lin2' = dinv*(h1@W2) (fp16) -> t'[n] = dinv*(relu(dinv*agg(lin2')+b2).v3)
//   -> s[n] = dinv*sum(t'[src]) + c3 -> segment-mean -> +bl
//
// R7 changes (spmm was issue/latency-bound: VALU 46%, HBM 30%, occ 60%):
//  * dinv[src] folded into stored rows (lin1', lin2', t') - no per-edge dinv
//    gather, one less FMA per edge, pool gather removed too.
//  * csr spans padded to multiples of 8 with a zero-row index (row N, zeroed
//    in k_v3) -> wave-uniform int4 csr loads (4 indices/instr, 16B aligned).
//  * spmm main loop unrolled to 16 edges (4x int4 + 16 gathers in flight).
//  Per 16 edges: mem instrs 48->20, VALU ~112->~80.

constexpr int N_NODES = 50000;
constexpr int N_EDGES = 1600000;
constexpr int F_IN_C  = 11;
constexpr int HC      = 128;
constexpr int G_C     = 1024;
constexpr int NPB     = 128;                        // nodes per bucket
constexpr int NB      = (N_NODES + NPB - 1) / NPB;  // 391 buckets
constexpr int CHUNK   = 8192;                       // edges per bin block
constexpr int NBLK_E  = (N_EDGES + CHUNK - 1) / CHUNK;
constexpr int ZROW    = N_NODES;                    // zero-row index for pads

// ---------------- fp16 pack/unpack ----------------

__device__ __forceinline__ unsigned pack_f16(float x, float y) {
  __half2 h = __floats2half2_rn(x, y);
  return *reinterpret_cast<unsigned*>(&h);
}

__device__ __forceinline__ float2 unpack_f16(unsigned u) {
  __half2 h = *reinterpret_cast<__half2*>(&u);
  return __half22float2(h);
}

// ---------------- CSR build ----------------

// A1: bucket histogram via per-block LDS counts.
__global__ __launch_bounds__(256) void k_bhist(const int* __restrict__ dst,
                                               int* __restrict__ bcnt) {
  __shared__ int hist[NB];
  int t = threadIdx.x;
  for (int b = t; b < NB; b += 256) hist[b] = 0;
  __syncthreads();
  long e0 = (long)blockIdx.x * CHUNK;
  for (int it = 0; it < CHUNK / 1024; ++it) {
    long e = e0 + it * 1024 + t * 4;
    if (e < N_EDGES) {
      int4 d4 = *(const int4*)(dst + e);
      atomicAdd(&hist[d4.x >> 7], 1);
      atomicAdd(&hist[d4.y >> 7], 1);
      atomicAdd(&hist[d4.z >> 7], 1);
      atomicAdd(&hist[d4.w >> 7], 1);
    }
  }
  __syncthreads();
  for (int b = t; b < NB; b += 256)
    if (hist[b]) atomicAdd(&bcnt[b], hist[b]);
}

// A2: exclusive prefix over bucket counts -> bucket base + cursor.
__global__ __launch_bounds__(512) void k_prefix(const int* __restrict__ bcnt,
                                                int* __restrict__ bbase,
                                                int* __restrict__ bcur) {
  __shared__ int sc[512];
  int t = threadIdx.x;
  int v = (t < NB) ? bcnt[t] : 0;
  sc[t] = v;
  __syncthreads();
  for (int off = 1; off < 512; off <<= 1) {
    int a = (t >= off) ? sc[t - off] : 0;
    __syncthreads();
    sc[t] += a;
    __syncthreads();
  }
  if (t < NB) {
    int excl = sc[t] - v;
    bbase[t] = excl;
    bcur[t]  = excl;
  }
}

// A3: bin edges into bucket regions as packed records (src | dst_local<<16).
__global__ __launch_bounds__(256) void k_bin(const int* __restrict__ src,
                                             const int* __restrict__ dst,
                                             int* __restrict__ bcur,
                                             unsigned int* __restrict__ pairs) {
  __shared__ int hist[NB], base[NB], loff[NB];
  int t = threadIdx.x;
  for (int b = t; b < NB; b += 256) { hist[b] = 0; loff[b] = 0; }
  __syncthreads();
  long e0 = (long)blockIdx.x * CHUNK;
  for (int it = 0; it < CHUNK / 1024; ++it) {
    long e = e0 + it * 1024 + t * 4;
    if (e < N_EDGES) {
      int4 d4 = *(const int4*)(dst + e);
      atomicAdd(&hist[d4.x >> 7], 1);
      atomicAdd(&hist[d4.y >> 7], 1);
      atomicAdd(&hist[d4.z >> 7], 1);
      atomicAdd(&hist[d4.w >> 7], 1);
    }
  }
  __syncthreads();
  for (int b = t; b < NB; b += 256)
    if (hist[b]) base[b] = atomicAdd(&bcur[b], hist[b]);
  __syncthreads();
  for (int it = 0; it < CHUNK / 1024; ++it) {
    long e = e0 + it * 1024 + t * 4;
    if (e < N_EDGES) {
      int4 s4 = *(const int4*)(src + e);
      int4 d4 = *(const int4*)(dst + e);
      {
        int b = d4.x >> 7;
        int l = atomicAdd(&loff[b], 1);
        pairs[base[b] + l] = (unsigned)s4.x | ((unsigned)(d4.x & 127) << 16);
      }
      {
        int b = d4.y >> 7;
        int l = atomicAdd(&loff[b], 1);
        pairs[base[b] + l] = (unsigned)s4.y | ((unsigned)(d4.y & 127) << 16);
      }
      {
        int b = d4.z >> 7;
        int l = atomicAdd(&loff[b], 1);
        pairs[base[b] + l] = (unsigned)s4.z | ((unsigned)(d4.z & 127) << 16);
      }
      {
        int b = d4.w >> 7;
        int l = atomicAdd(&loff[b], 1);
        pairs[base[b] + l] = (unsigned)s4.w | ((unsigned)(d4.w & 127) << 16);
      }
    }
  }
}

// B: per-bucket CSR build. Spans padded to x8 with ZROW entries.
__global__ __launch_bounds__(256) void k_build(const unsigned int* __restrict__ pairs,
                                               const int* __restrict__ bbase,
                                               const int* __restrict__ bcur,
                                               int* __restrict__ total,
                                               int* __restrict__ start,
                                               int* __restrict__ deg,
                                               float* __restrict__ dinv,
                                               int* __restrict__ csr) {
  __shared__ int cntL[NPB], sc[NPB];
  __shared__ int csrBaseL;
  int t = threadIdx.x;
  int b = blockIdx.x;
  int nodeBase = b * NPB;
  int nib = min(NPB, N_NODES - nodeBase);
  int pbase = bbase[b];
  int pend  = bcur[b];         // after A3: base + size
  int size  = pend - pbase;
  if (t < NPB) cntL[t] = 0;
  __syncthreads();
  for (int p = t; p < size; p += 256)
    atomicAdd(&cntL[pairs[pbase + p] >> 16], 1);
  __syncthreads();
  int d = 0, dpad = 0;
  if (t < NPB && t < nib) {
    d = cntL[t] + 1;                 // +1 self loop
    dpad = (d + 7) & ~7;             // span padded to multiple of 8
  }
  if (t < NPB) sc[t] = dpad;
  __syncthreads();
  for (int off = 1; off < NPB; off <<= 1) {
    int a = 0;
    if (t < NPB && t >= off) a = sc[t - off];
    __syncthreads();
    if (t < NPB) sc[t] += a;
    __syncthreads();
  }
  if (t == 0) csrBaseL = atomicAdd(total, sc[NPB - 1]);
  __syncthreads();
  int csrBase = csrBaseL;
  if (t < nib) {
    int excl = sc[t] - dpad;
    int n = nodeBase + t;
    int s = csrBase + excl;
    start[n] = s;
    deg[n]   = dpad;                 // spmm/pool iterate padded span
    dinv[n]  = rsqrtf((float)d);
    csr[s]   = n;                    // self-loop slot
    for (int k = d; k < dpad; ++k) csr[s + k] = ZROW;  // zero-row pads
    cntL[t]  = excl + 1;             // local cursor (after self loop)
  }
  __syncthreads();
  for (int p = t; p < size; p += 256) {
    unsigned v = pairs[pbase + p];
    int loc = atomicAdd(&cntL[v >> 16], 1);
    csr[csrBase + loc] = (int)(v & 0xFFFFu);
  }
}

// ---------------- dense pieces ----------------

// lin1' = dinv * (x @ W1), packed fp16. 4 nodes per 256-thread block.
__global__ __launch_bounds__(256) void k_lin1(const float* __restrict__ x,
                                              const float* __restrict__ W1,
                                              const float* __restrict__ dinv,
                                              unsigned* __restrict__ out) {
  __shared__ float w_s[F_IN_C * HC];
  for (int i = threadIdx.x; i < F_IN_C * HC; i += 256) w_s[i] = W1[i];
  __syncthreads();
  int lane = threadIdx.x & 63;
  int sub  = threadIdx.x >> 6;            // 4 nodes per block
  for (int n = blockIdx.x * 4 + sub; n < N_NODES; n += gridDim.x * 4) {
    const float* xr = x + (size_t)n * F_IN_C;
    float ax = 0.f, ay = 0.f;
#pragma unroll
    for (int k = 0; k < F_IN_C; ++k) {
      float xv = xr[k];
      ax += xv * w_s[k * HC + 2 * lane];
      ay += xv * w_s[k * HC + 2 * lane + 1];
    }
    float dn = dinv[n];
    out[(size_t)n * 64 + lane] = pack_f16(ax * dn, ay * dn);
  }
}

// lin2' = dinv * (h1 @ W2) (fp32 in, packed fp16 out). 16 nodes/128 threads.
// Thread t: column pair tp = t&63, row group rg = t>>6 (8 rows each).
__global__ __launch_bounds__(128) void k_gemm(const float* __restrict__ in,
                                              const float* __restrict__ W,
                                              const float* __restrict__ dinv,
                                              unsigned* __restrict__ out) {
  __shared__ float in_s[16][HC];
  int t  = threadIdx.x;
  int n0 = blockIdx.x * 16;
#pragma unroll
  for (int r = 0; r < 16; ++r) in_s[r][t] = in[(size_t)(n0 + r) * HC + t];
  __syncthreads();
  int tp = t & 63;
  int rg = t >> 6;
  float accx[8], accy[8];
#pragma unroll
  for (int r = 0; r < 8; ++r) { accx[r] = 0.f; accy[r] = 0.f; }
  for (int k = 0; k < HC; ++k) {
    float2 w2 = *(const float2*)(W + k * HC + 2 * tp);
#pragma unroll
    for (int r = 0; r < 8; ++r) {
      float a = in_s[rg * 8 + r][k];        // wave-uniform LDS broadcast
      accx[r] += a * w2.x;
      accy[r] += a * w2.y;
    }
  }
#pragma unroll
  for (int r = 0; r < 8; ++r) {
    int n = n0 + rg * 8 + r;
    float dn = dinv[n];
    out[(size_t)n * 64 + tp] = pack_f16(accx[r] * dn, accy[r] * dn);
  }
}

// v3 = W3 @ Wl (128), c3 = b3 . Wl. Also zeros pad rows / slots.
__global__ __launch_bounds__(128) void k_v3(const float* __restrict__ W3,
                                            const float* __restrict__ b3,
                                            const float* __restrict__ Wl,
                                            float* __restrict__ v3,
                                            float* __restrict__ c3,
                                            unsigned* __restrict__ lin1,
                                            unsigned* __restrict__ lin2,
                                            float* __restrict__ tbuf) {
  int k = threadIdx.x;
  float acc = 0.f;
  for (int j = 0; j < HC; ++j) acc += W3[k * HC + j] * Wl[j];
  v3[k] = acc;
  // zero-row init (row ZROW of lin1/lin2, tbuf[ZROW])
  if (k < 64) {
    lin1[(size_t)ZROW * 64 + k] = 0u;
    lin2[(size_t)ZROW * 64 + k] = 0u;
  }
  if (k == 64) tbuf[ZROW] = 0.f;
  __shared__ float red[128];
  red[k] = b3[k] * Wl[k];
  __syncthreads();
  for (int s = 64; s > 0; s >>= 1) {
    if (k < s) red[k] += red[k + s];
    __syncthreads();
  }
  if (k == 0) *c3 = red[0];
}

// ---------------- sparse aggregation ----------------

// Gathers prescaled packed-fp16 rows; csr via wave-uniform int4 loads.
// MODE 0: out[n][:] = relu(dinv[n]*agg + bias)       (float2/lane, fp32)
// MODE 1: out[n]    = dinv[n]*(relu(dinv[n]*agg + bias) . v3)  (scalar)
template <int MODE>
__global__ __launch_bounds__(256) void k_spmm(const unsigned* __restrict__ lin,
                                              const float* __restrict__ dinv,
                                              const int* __restrict__ start,
                                              const int* __restrict__ deg,
                                              const int* __restrict__ csr,
                                              const float* __restrict__ bias,
                                              const float* __restrict__ v3,
                                              float* __restrict__ out) {
  int wv = threadIdx.x >> 6, lane = threadIdx.x & 63;
  int n = blockIdx.x * 4 + wv;
  if (n >= N_NODES) return;
  int s0 = start[n], d = deg[n];          // d is a multiple of 8, span aligned
  float dn = dinv[n];
  float ax[8], ay[8];
#pragma unroll
  for (int u = 0; u < 8; ++u) { ax[u] = 0.f; ay[u] = 0.f; }
  int i = 0;
  for (; i + 16 <= d; i += 16) {
    int4 c0 = *(const int4*)(csr + s0 + i);
    int4 c1 = *(const int4*)(csr + s0 + i + 4);
    int4 c2 = *(const int4*)(csr + s0 + i + 8);
    int4 c3i = *(const int4*)(csr + s0 + i + 12);
    unsigned q[16];
    q[0]  = lin[(size_t)c0.x * 64 + lane];
    q[1]  = lin[(size_t)c0.y * 64 + lane];
    q[2]  = lin[(size_t)c0.z * 64 + lane];
    q[3]  = lin[(size_t)c0.w * 64 + lane];
    q[4]  = lin[(size_t)c1.x * 64 + lane];
    q[5]  = lin[(size_t)c1.y * 64 + lane];
    q[6]  = lin[(size_t)c1.z * 64 + lane];
    q[7]  = lin[(size_t)c1.w * 64 + lane];
    q[8]  = lin[(size_t)c2.x * 64 + lane];
    q[9]  = lin[(size_t)c2.y * 64 + lane];
    q[10] = lin[(size_t)c2.z * 64 + lane];
    q[11] = lin[(size_t)c2.w * 64 + lane];
    q[12] = lin[(size_t)c3i.x * 64 + lane];
    q[13] = lin[(size_t)c3i.y * 64 + lane];
    q[14] = lin[(size_t)c3i.z * 64 + lane];
    q[15] = lin[(size_t)c3i.w * 64 + lane];
#pragma unroll
    for (int u = 0; u < 16; ++u) {
      float2 v = unpack_f16(q[u]);
      ax[u & 7] += v.x;
      ay[u & 7] += v.y;
    }
  }
  if (i < d) {                            // exactly one 8-block remains
    int4 c0 = *(const int4*)(csr + s0 + i);
    int4 c1 = *(const int4*)(csr + s0 + i + 4);
    unsigned q[8];
    q[0] = lin[(size_t)c0.x * 64 + lane];
    q[1] = lin[(size_t)c0.y * 64 + lane];
    q[2] = lin[(size_t)c0.z * 64 + lane];
    q[3] = lin[(size_t)c0.w * 64 + lane];
    q[4] = lin[(size_t)c1.x * 64 + lane];
    q[5] = lin[(size_t)c1.y * 64 + lane];
    q[6] = lin[(size_t)c1.z * 64 + lane];
    q[7] = lin[(size_t)c1.w * 64 + lane];
#pragma unroll
    for (int u = 0; u < 8; ++u) {
      float2 v = unpack_f16(q[u]);
      ax[u] += v.x;
      ay[u] += v.y;
    }
  }
  float sx = ((ax[0] + ax[1]) + (ax[2] + ax[3])) + ((ax[4] + ax[5]) + (ax[6] + ax[7]));
  float sy = ((ay[0] + ay[1]) + (ay[2] + ay[3])) + ((ay[4] + ay[5]) + (ay[6] + ay[7]));
  sx = fmaxf(sx * dn + bias[lane * 2], 0.f);
  sy = fmaxf(sy * dn + bias[lane * 2 + 1], 0.f);
  if (MODE == 0) {
    ((float2*)out)[(size_t)n * 64 + lane] = make_float2(sx, sy);
  } else {
    float2 vv = ((const float2*)v3)[lane];
    float p = sx * vv.x + sy * vv.y;
#pragma unroll
    for (int o = 32; o > 0; o >>= 1) p += __shfl_down(p, o, 64);
    if (lane == 0) out[n] = p * dn;       // prescale for the pool pass
  }
}

// s[n] = dinv[n] * sum_e t'[src] + c3; segment-sum into graphs.
__global__ __launch_bounds__(256) void k_spmv_pool(const float* __restrict__ t,
                                                   const float* __restrict__ dinv,
                                                   const int* __restrict__ start,
                                                   const int* __restrict__ deg,
                                                   const int* __restrict__ csr,
                                                   const float* __restrict__ c3,
                                                   const int* __restrict__ batch,
                                                   float* __restrict__ ssum,
                                                   int* __restrict__ cntg) {
  int n = blockIdx.x * 256 + threadIdx.x;
  if (n >= N_NODES) return;
  int s0 = start[n], d = deg[n];          // padded span; t[ZROW]=0
  float a0 = 0.f, a1 = 0.f, a2 = 0.f, a3 = 0.f;
  for (int i = 0; i + 4 <= d; i += 4) {
    int4 c = *(const int4*)(csr + s0 + i);
    a0 += t[c.x];
    a1 += t[c.y];
    a2 += t[c.z];
    a3 += t[c.w];
  }
  float acc = ((a0 + a1) + (a2 + a3)) * dinv[n] + *c3;
  int g = batch[n];
  atomicAdd(&ssum[g], acc);
  atomicAdd(&cntg[g], 1);
}

__global__ __launch_bounds__(256) void k_out(const float* __restrict__ ssum,
                                             const int* __restrict__ cntg,
                                             const float* __restrict__ bl,
                                             float* __restrict__ out) {
  int g = blockIdx.x * 256 + threadIdx.x;
  if (g < G_C) out[g] = ssum[g] / fmaxf((float)cntg[g], 1.f) + bl[0];
}

// ---------------- launch ----------------

extern "C" void kernel_launch(void* const* d_in, const int* in_sizes, int n_in,
                              void* d_out, int out_size, void* d_ws, size_t ws_size,
                              hipStream_t stream) {
  const float* x     = (const float*)d_in[0];
  const int*   ei    = (const int*)d_in[1];
  const int*   srcE  = ei;
  const int*   dstE  = ei + N_EDGES;
  const int*   batch = (const int*)d_in[2];
  const float* W1 = (const float*)d_in[3];
  const float* b1 = (const float*)d_in[4];
  const float* W2 = (const float*)d_in[5];
  const float* b2 = (const float*)d_in[6];
  const float* W3 = (const float*)d_in[7];
  const float* b3 = (const float*)d_in[8];
  const float* Wl = (const float*)d_in[9];
  const float* bl = (const float*)d_in[10];
  float* out = (float*)d_out;

  // workspace layout (16B aligned slices)
  size_t off = 0;
  auto alloc = [&](size_t bytes) -> char* {
    char* p = (char*)d_ws + off;
    off = (off + bytes + 15) & ~(size_t)15;
    return p;
  };
  // bufA: pairs (6.4MB, CSR build) -> lin1' fp16 + lin2' fp16 ((N+1) rows each)
  char* bufA = alloc((size_t)(N_NODES + 1) * 2 * 256);     // 25.6 MB + 512B
  float* bufB = (float*)alloc((size_t)N_NODES * HC * 4);   // 25.6 MB (h1 fp32)
  unsigned* pairs = (unsigned*)bufA;
  unsigned* lin1  = (unsigned*)bufA;                       // (N+1)*64 uints
  unsigned* lin2  = (unsigned*)(bufA + (size_t)(N_NODES + 1) * 256);
  float* dinv = (float*)alloc((size_t)N_NODES * 4);
  float* tbuf = (float*)alloc((size_t)(N_NODES + 1) * 4);
  float* v3   = (float*)alloc(HC * 4);
  float* c3   = (float*)alloc(16);
  int* startA = (int*)alloc((size_t)N_NODES * 4);
  int* degA   = (int*)alloc((size_t)N_NODES * 4);
  // csr: padded spans (self-loop + edges + pad-to-8) <= E + 8*N
  int* csr    = (int*)alloc((size_t)(N_EDGES + 8 * N_NODES) * 4);  // 8.0 MB
  int* bbase  = (int*)alloc(NB * 4);
  int* bcur   = (int*)alloc(NB * 4);
  // zero zone: bcnt | total | ssum | cntg
  size_t zz_bytes = NB * 4 + 16 + G_C * 4 + G_C * 4;
  char* zz = alloc(zz_bytes);
  int*   bcnt = (int*)zz;
  int*   total= (int*)(zz + NB * 4);
  float* ssum = (float*)(zz + NB * 4 + 16);
  int*   cntg = (int*)(zz + NB * 4 + 16 + G_C * 4);

  hipMemsetAsync(zz, 0, zz_bytes, stream);

  k_bhist<<<NBLK_E, 256, 0, stream>>>(dstE, bcnt);
  k_prefix<<<1, 512, 0, stream>>>(bcnt, bbase, bcur);
  k_bin<<<NBLK_E, 256, 0, stream>>>(srcE, dstE, bcur, pairs);
  k_build<<<NB, 256, 0, stream>>>(pairs, bbase, bcur, total, startA, degA, dinv, csr);
  k_v3<<<1, 128, 0, stream>>>(W3, b3, Wl, v3, c3, lin1, lin2, tbuf);

  k_lin1<<<N_NODES / 4, 256, 0, stream>>>(x, W1, dinv, lin1);
  k_spmm<0><<<N_NODES / 4, 256, 0, stream>>>(lin1, dinv, startA, degA, csr, b1, v3, bufB);
  k_gemm<<<N_NODES / 16, 128, 0, stream>>>(bufB, W2, dinv, lin2);
  k_spmm<1><<<N_NODES / 4, 256, 0, stream>>>(lin2, dinv, startA, degA, csr, b2, v3, tbuf);
  k_spmv_pool<<<(N_NODES + 255) / 256, 256, 0, stream>>>(tbuf, dinv, startA, degA, csr,
                                                         c3, batch, ssum, cntg);
  k_out<<<(G_C + 255) / 256, 256, 0, stream>>>(ssum, cntg, bl, out);
}

// Round 8
// 241.089 us; speedup vs baseline: 2.2803x; 1.0168x over previous
//
#include <hip/hip_runtime.h>
#include <hip/hip_fp16.h>

// GCN: N=50000 nodes, E=1.6M edges (+N self-loops), F_IN=11, H=128, G=1024, T=1.
// Pipeline (layer-3 folded into v3 = W3@Wl, c3 = b3 . Wl):
//   binned counting-sort CSR build (A1 hist -> A2 prefix -> A3 bin -> B build)
//   -> lin1' = dinv*(x@W1) (fp16) -> h1 = relu(dinv*agg(lin1')+b1) (fp32)
//   -> lin2' = dinv*(h1@W2) (fp16) -> t'[n] = dinv*(relu(dinv*agg(lin2')+b2).v3)
//   -> s[n] = dinv*sum(t'[src]) + c3 -> segment-mean -> +bl
//
// R8 changes (spmm half-latency-bound: VALU 50%, HBM 45%, occ 50%):
//  * k_spmm software pipeline: csr block kept 1 iter ahead, gathers 1 iter in
//    flight (issue qB -> prefetch csr -> consume qA -> rotate). Hides the
//    per-8-edge csr->gather->consume dependency chain.
//  * k_gemm rebalanced: 32 nodes/block, 4 cols x 8 rows per thread
//    (FMA:LDS 4:1, float4 W loads, uint2 packed stores).

constexpr int N_NODES = 50000;
constexpr int N_EDGES = 1600000;
constexpr int F_IN_C  = 11;
constexpr int HC      = 128;
constexpr int G_C     = 1024;
constexpr int NPB     = 128;                        // nodes per bucket
constexpr int NB      = (N_NODES + NPB - 1) / NPB;  // 391 buckets
constexpr int CHUNK   = 8192;                       // edges per bin block
constexpr int NBLK_E  = (N_EDGES + CHUNK - 1) / CHUNK;
constexpr int ZROW    = N_NODES;                    // zero-row index for pads
constexpr int GM      = 32;                         // nodes per gemm block

// ---------------- fp16 pack/unpack ----------------

__device__ __forceinline__ unsigned pack_f16(float x, float y) {
  __half2 h = __floats2half2_rn(x, y);
  return *reinterpret_cast<unsigned*>(&h);
}

__device__ __forceinline__ float2 unpack_f16(unsigned u) {
  __half2 h = *reinterpret_cast<__half2*>(&u);
  return __half22float2(h);
}

// ---------------- CSR build ----------------

// A1: bucket histogram via per-block LDS counts.
__global__ __launch_bounds__(256) void k_bhist(const int* __restrict__ dst,
                                               int* __restrict__ bcnt) {
  __shared__ int hist[NB];
  int t = threadIdx.x;
  for (int b = t; b < NB; b += 256) hist[b] = 0;
  __syncthreads();
  long e0 = (long)blockIdx.x * CHUNK;
  for (int it = 0; it < CHUNK / 1024; ++it) {
    long e = e0 + it * 1024 + t * 4;
    if (e < N_EDGES) {
      int4 d4 = *(const int4*)(dst + e);
      atomicAdd(&hist[d4.x >> 7], 1);
      atomicAdd(&hist[d4.y >> 7], 1);
      atomicAdd(&hist[d4.z >> 7], 1);
      atomicAdd(&hist[d4.w >> 7], 1);
    }
  }
  __syncthreads();
  for (int b = t; b < NB; b += 256)
    if (hist[b]) atomicAdd(&bcnt[b], hist[b]);
}

// A2: exclusive prefix over bucket counts -> bucket base + cursor.
__global__ __launch_bounds__(512) void k_prefix(const int* __restrict__ bcnt,
                                                int* __restrict__ bbase,
                                                int* __restrict__ bcur) {
  __shared__ int sc[512];
  int t = threadIdx.x;
  int v = (t < NB) ? bcnt[t] : 0;
  sc[t] = v;
  __syncthreads();
  for (int off = 1; off < 512; off <<= 1) {
    int a = (t >= off) ? sc[t - off] : 0;
    __syncthreads();
    sc[t] += a;
    __syncthreads();
  }
  if (t < NB) {
    int excl = sc[t] - v;
    bbase[t] = excl;
    bcur[t]  = excl;
  }
}

// A3: bin edges into bucket regions as packed records (src | dst_local<<16).
__global__ __launch_bounds__(256) void k_bin(const int* __restrict__ src,
                                             const int* __restrict__ dst,
                                             int* __restrict__ bcur,
                                             unsigned int* __restrict__ pairs) {
  __shared__ int hist[NB], base[NB], loff[NB];
  int t = threadIdx.x;
  for (int b = t; b < NB; b += 256) { hist[b] = 0; loff[b] = 0; }
  __syncthreads();
  long e0 = (long)blockIdx.x * CHUNK;
  for (int it = 0; it < CHUNK / 1024; ++it) {
    long e = e0 + it * 1024 + t * 4;
    if (e < N_EDGES) {
      int4 d4 = *(const int4*)(dst + e);
      atomicAdd(&hist[d4.x >> 7], 1);
      atomicAdd(&hist[d4.y >> 7], 1);
      atomicAdd(&hist[d4.z >> 7], 1);
      atomicAdd(&hist[d4.w >> 7], 1);
    }
  }
  __syncthreads();
  for (int b = t; b < NB; b += 256)
    if (hist[b]) base[b] = atomicAdd(&bcur[b], hist[b]);
  __syncthreads();
  for (int it = 0; it < CHUNK / 1024; ++it) {
    long e = e0 + it * 1024 + t * 4;
    if (e < N_EDGES) {
      int4 s4 = *(const int4*)(src + e);
      int4 d4 = *(const int4*)(dst + e);
      {
        int b = d4.x >> 7;
        int l = atomicAdd(&loff[b], 1);
        pairs[base[b] + l] = (unsigned)s4.x | ((unsigned)(d4.x & 127) << 16);
      }
      {
        int b = d4.y >> 7;
        int l = atomicAdd(&loff[b], 1);
        pairs[base[b] + l] = (unsigned)s4.y | ((unsigned)(d4.y & 127) << 16);
      }
      {
        int b = d4.z >> 7;
        int l = atomicAdd(&loff[b], 1);
        pairs[base[b] + l] = (unsigned)s4.z | ((unsigned)(d4.z & 127) << 16);
      }
      {
        int b = d4.w >> 7;
        int l = atomicAdd(&loff[b], 1);
        pairs[base[b] + l] = (unsigned)s4.w | ((unsigned)(d4.w & 127) << 16);
      }
    }
  }
}

// B: per-bucket CSR build. Spans padded to x8 with ZROW entries.
__global__ __launch_bounds__(256) void k_build(const unsigned int* __restrict__ pairs,
                                               const int* __restrict__ bbase,
                                               const int* __restrict__ bcur,
                                               int* __restrict__ total,
                                               int* __restrict__ start,
                                               int* __restrict__ deg,
                                               float* __restrict__ dinv,
                                               int* __restrict__ csr) {
  __shared__ int cntL[NPB], sc[NPB];
  __shared__ int csrBaseL;
  int t = threadIdx.x;
  int b = blockIdx.x;
  int nodeBase = b * NPB;
  int nib = min(NPB, N_NODES - nodeBase);
  int pbase = bbase[b];
  int pend  = bcur[b];         // after A3: base + size
  int size  = pend - pbase;
  if (t < NPB) cntL[t] = 0;
  __syncthreads();
  for (int p = t; p < size; p += 256)
    atomicAdd(&cntL[pairs[pbase + p] >> 16], 1);
  __syncthreads();
  int d = 0, dpad = 0;
  if (t < NPB && t < nib) {
    d = cntL[t] + 1;                 // +1 self loop
    dpad = (d + 7) & ~7;             // span padded to multiple of 8
  }
  if (t < NPB) sc[t] = dpad;
  __syncthreads();
  for (int off = 1; off < NPB; off <<= 1) {
    int a = 0;
    if (t < NPB && t >= off) a = sc[t - off];
    __syncthreads();
    if (t < NPB) sc[t] += a;
    __syncthreads();
  }
  if (t == 0) csrBaseL = atomicAdd(total, sc[NPB - 1]);
  __syncthreads();
  int csrBase = csrBaseL;
  if (t < nib) {
    int excl = sc[t] - dpad;
    int n = nodeBase + t;
    int s = csrBase + excl;
    start[n] = s;
    deg[n]   = dpad;                 // spmm/pool iterate padded span
    dinv[n]  = rsqrtf((float)d);
    csr[s]   = n;                    // self-loop slot
    for (int k = d; k < dpad; ++k) csr[s + k] = ZROW;  // zero-row pads
    cntL[t]  = excl + 1;             // local cursor (after self loop)
  }
  __syncthreads();
  for (int p = t; p < size; p += 256) {
    unsigned v = pairs[pbase + p];
    int loc = atomicAdd(&cntL[v >> 16], 1);
    csr[csrBase + loc] = (int)(v & 0xFFFFu);
  }
}

// ---------------- dense pieces ----------------

// lin1' = dinv * (x @ W1), packed fp16. 4 nodes per 256-thread block.
__global__ __launch_bounds__(256) void k_lin1(const float* __restrict__ x,
                                              const float* __restrict__ W1,
                                              const float* __restrict__ dinv,
                                              unsigned* __restrict__ out) {
  __shared__ float w_s[F_IN_C * HC];
  for (int i = threadIdx.x; i < F_IN_C * HC; i += 256) w_s[i] = W1[i];
  __syncthreads();
  int lane = threadIdx.x & 63;
  int sub  = threadIdx.x >> 6;            // 4 nodes per block
  for (int n = blockIdx.x * 4 + sub; n < N_NODES; n += gridDim.x * 4) {
    const float* xr = x + (size_t)n * F_IN_C;
    float ax = 0.f, ay = 0.f;
#pragma unroll
    for (int k = 0; k < F_IN_C; ++k) {
      float xv = xr[k];
      ax += xv * w_s[k * HC + 2 * lane];
      ay += xv * w_s[k * HC + 2 * lane + 1];
    }
    float dn = dinv[n];
    out[(size_t)n * 64 + lane] = pack_f16(ax * dn, ay * dn);
  }
}

// lin2' = dinv * (h1 @ W2) (fp32 in, packed fp16 out). 32 nodes / 128 threads.
// Thread t: cols 4*(t&31)..+3, rows (t>>5)*8..+7. FMA:LDS = 4:1.
__global__ __launch_bounds__(128) void k_gemm(const float* __restrict__ in,
                                              const float* __restrict__ W,
                                              const float* __restrict__ dinv,
                                              unsigned* __restrict__ out) {
  __shared__ float in_s[GM][HC];
  int t  = threadIdx.x;
  int n0 = blockIdx.x * GM;
  int rows = min(GM, N_NODES - n0);
  const float4* inv4 = (const float4*)(in + (size_t)n0 * HC);
  float4* s4 = (float4*)&in_s[0][0];
  if (rows == GM) {
#pragma unroll
    for (int r = 0; r < 8; ++r) s4[t + r * 128] = inv4[t + r * 128];
  } else {
#pragma unroll
    for (int r = 0; r < 8; ++r) {
      int fv = t + r * 128;                    // float4 index; row = fv/32
      s4[fv] = (fv / 32 < rows) ? inv4[fv] : make_float4(0.f, 0.f, 0.f, 0.f);
    }
  }
  __syncthreads();
  int tp = t & 31;                             // col group (4 cols)
  int rg = t >> 5;                             // row group (8 rows)
  float a0[8], a1[8], a2[8], a3[8];
#pragma unroll
  for (int r = 0; r < 8; ++r) { a0[r] = 0.f; a1[r] = 0.f; a2[r] = 0.f; a3[r] = 0.f; }
  for (int k = 0; k < HC; ++k) {
    float4 w4 = *(const float4*)(W + k * HC + 4 * tp);
#pragma unroll
    for (int r = 0; r < 8; ++r) {
      float a = in_s[rg * 8 + r][k];           // half-wave-uniform broadcast
      a0[r] += a * w4.x;
      a1[r] += a * w4.y;
      a2[r] += a * w4.z;
      a3[r] += a * w4.w;
    }
  }
#pragma unroll
  for (int r = 0; r < 8; ++r) {
    int n = n0 + rg * 8 + r;
    if (n < N_NODES) {
      float dn = dinv[n];
      uint2 pk;
      pk.x = pack_f16(a0[r] * dn, a1[r] * dn);
      pk.y = pack_f16(a2[r] * dn, a3[r] * dn);
      *(uint2*)&out[(size_t)n * 64 + 2 * tp] = pk;
    }
  }
}

// v3 = W3 @ Wl (128), c3 = b3 . Wl. Also zeros pad rows / slots.
__global__ __launch_bounds__(128) void k_v3(const float* __restrict__ W3,
                                            const float* __restrict__ b3,
                                            const float* __restrict__ Wl,
                                            float* __restrict__ v3,
                                            float* __restrict__ c3,
                                            unsigned* __restrict__ lin1,
                                            unsigned* __restrict__ lin2,
                                            float* __restrict__ tbuf) {
  int k = threadIdx.x;
  float acc = 0.f;
  for (int j = 0; j < HC; ++j) acc += W3[k * HC + j] * Wl[j];
  v3[k] = acc;
  // zero-row init (row ZROW of lin1/lin2, tbuf[ZROW])
  if (k < 64) {
    lin1[(size_t)ZROW * 64 + k] = 0u;
    lin2[(size_t)ZROW * 64 + k] = 0u;
  }
  if (k == 64) tbuf[ZROW] = 0.f;
  __shared__ float red[128];
  red[k] = b3[k] * Wl[k];
  __syncthreads();
  for (int s = 64; s > 0; s >>= 1) {
    if (k < s) red[k] += red[k + s];
    __syncthreads();
  }
  if (k == 0) *c3 = red[0];
}

// ---------------- sparse aggregation ----------------

// Gathers prescaled packed-fp16 rows; csr via wave-uniform int4 loads.
// Software pipeline: csr 1 block ahead, gathers 1 block in flight.
// MODE 0: out[n][:] = relu(dinv[n]*agg + bias)       (float2/lane, fp32)
// MODE 1: out[n]    = dinv[n]*(relu(dinv[n]*agg + bias) . v3)  (scalar)
template <int MODE>
__global__ __launch_bounds__(256) void k_spmm(const unsigned* __restrict__ lin,
                                              const float* __restrict__ dinv,
                                              const int* __restrict__ start,
                                              const int* __restrict__ deg,
                                              const int* __restrict__ csr,
                                              const float* __restrict__ bias,
                                              const float* __restrict__ v3,
                                              float* __restrict__ out) {
  int wv = threadIdx.x >> 6, lane = threadIdx.x & 63;
  int n = blockIdx.x * 4 + wv;
  if (n >= N_NODES) return;
  int s0 = start[n], d = deg[n];          // multiple of 8, >= 8
  float dn = dinv[n];
  const unsigned* lp = lin + lane;        // per-lane gather base
  float ax[8], ay[8];
#pragma unroll
  for (int u = 0; u < 8; ++u) { ax[u] = 0.f; ay[u] = 0.f; }
  int nb = d >> 3;
  // prologue: csr block 0, gathers block 0, csr block 1
  int4 cc0 = *(const int4*)(csr + s0);
  int4 cc1 = *(const int4*)(csr + s0 + 4);
  unsigned qA[8];
  qA[0] = lp[(size_t)cc0.x * 64];
  qA[1] = lp[(size_t)cc0.y * 64];
  qA[2] = lp[(size_t)cc0.z * 64];
  qA[3] = lp[(size_t)cc0.w * 64];
  qA[4] = lp[(size_t)cc1.x * 64];
  qA[5] = lp[(size_t)cc1.y * 64];
  qA[6] = lp[(size_t)cc1.z * 64];
  qA[7] = lp[(size_t)cc1.w * 64];
  if (nb > 1) {
    cc0 = *(const int4*)(csr + s0 + 8);
    cc1 = *(const int4*)(csr + s0 + 12);
  }
  for (int b = 1; b < nb; ++b) {
    // issue gathers for block b (csr arrived during previous consume)
    unsigned qB[8];
    qB[0] = lp[(size_t)cc0.x * 64];
    qB[1] = lp[(size_t)cc0.y * 64];
    qB[2] = lp[(size_t)cc0.z * 64];
    qB[3] = lp[(size_t)cc0.w * 64];
    qB[4] = lp[(size_t)cc1.x * 64];
    qB[5] = lp[(size_t)cc1.y * 64];
    qB[6] = lp[(size_t)cc1.z * 64];
    qB[7] = lp[(size_t)cc1.w * 64];
    // prefetch csr for block b+1
    if (b + 1 < nb) {
      cc0 = *(const int4*)(csr + s0 + (b + 1) * 8);
      cc1 = *(const int4*)(csr + s0 + (b + 1) * 8 + 4);
    }
    // consume gathers of block b-1 (in flight for one full iteration)
#pragma unroll
    for (int u = 0; u < 8; ++u) {
      float2 v = unpack_f16(qA[u]);
      ax[u] += v.x;
      ay[u] += v.y;
    }
#pragma unroll
    for (int u = 0; u < 8; ++u) qA[u] = qB[u];
  }
  // epilogue: consume last block
#pragma unroll
  for (int u = 0; u < 8; ++u) {
    float2 v = unpack_f16(qA[u]);
    ax[u] += v.x;
    ay[u] += v.y;
  }
  float sx = ((ax[0] + ax[1]) + (ax[2] + ax[3])) + ((ax[4] + ax[5]) + (ax[6] + ax[7]));
  float sy = ((ay[0] + ay[1]) + (ay[2] + ay[3])) + ((ay[4] + ay[5]) + (ay[6] + ay[7]));
  sx = fmaxf(sx * dn + bias[lane * 2], 0.f);
  sy = fmaxf(sy * dn + bias[lane * 2 + 1], 0.f);
  if (MODE == 0) {
    ((float2*)out)[(size_t)n * 64 + lane] = make_float2(sx, sy);
  } else {
    float2 vv = ((const float2*)v3)[lane];
    float p = sx * vv.x + sy * vv.y;
#pragma unroll
    for (int o = 32; o > 0; o >>= 1) p += __shfl_down(p, o, 64);
    if (lane == 0) out[n] = p * dn;       // prescale for the pool pass
  }
}

// s[n] = dinv[n] * sum_e t'[src] + c3; segment-sum into graphs.
__global__ __launch_bounds__(256) void k_spmv_pool(const float* __restrict__ t,
                                                   const float* __restrict__ dinv,
                                                   const int* __restrict__ start,
                                                   const int* __restrict__ deg,
                                                   const int* __restrict__ csr,
                                                   const float* __restrict__ c3,
                                                   const int* __restrict__ batch,
                                                   float* __restrict__ ssum,
                                                   int* __restrict__ cntg) {
  int n = blockIdx.x * 256 + threadIdx.x;
  if (n >= N_NODES) return;
  int s0 = start[n], d = deg[n];          // padded span; t[ZROW]=0
  float a0 = 0.f, a1 = 0.f, a2 = 0.f, a3 = 0.f;
  for (int i = 0; i + 4 <= d; i += 4) {
    int4 c = *(const int4*)(csr + s0 + i);
    a0 += t[c.x];
    a1 += t[c.y];
    a2 += t[c.z];
    a3 += t[c.w];
  }
  float acc = ((a0 + a1) + (a2 + a3)) * dinv[n] + *c3;
  int g = batch[n];
  atomicAdd(&ssum[g], acc);
  atomicAdd(&cntg[g], 1);
}

__global__ __launch_bounds__(256) void k_out(const float* __restrict__ ssum,
                                             const int* __restrict__ cntg,
                                             const float* __restrict__ bl,
                                             float* __restrict__ out) {
  int g = blockIdx.x * 256 + threadIdx.x;
  if (g < G_C) out[g] = ssum[g] / fmaxf((float)cntg[g], 1.f) + bl[0];
}

// ---------------- launch ----------------

extern "C" void kernel_launch(void* const* d_in, const int* in_sizes, int n_in,
                              void* d_out, int out_size, void* d_ws, size_t ws_size,
                              hipStream_t stream) {
  const float* x     = (const float*)d_in[0];
  const int*   ei    = (const int*)d_in[1];
  const int*   srcE  = ei;
  const int*   dstE  = ei + N_EDGES;
  const int*   batch = (const int*)d_in[2];
  const float* W1 = (const float*)d_in[3];
  const float* b1 = (const float*)d_in[4];
  const float* W2 = (const float*)d_in[5];
  const float* b2 = (const float*)d_in[6];
  const float* W3 = (const float*)d_in[7];
  const float* b3 = (const float*)d_in[8];
  const float* Wl = (const float*)d_in[9];
  const float* bl = (const float*)d_in[10];
  float* out = (float*)d_out;

  // workspace layout (16B aligned slices)
  size_t off = 0;
  auto alloc = [&](size_t bytes) -> char* {
    char* p = (char*)d_ws + off;
    off = (off + bytes + 15) & ~(size_t)15;
    return p;
  };
  // bufA: pairs (6.4MB, CSR build) -> lin1' fp16 + lin2' fp16 ((N+1) rows each)
  char* bufA = alloc((size_t)(N_NODES + 1) * 2 * 256);     // 25.6 MB + 512B
  float* bufB = (float*)alloc((size_t)N_NODES * HC * 4);   // 25.6 MB (h1 fp32)
  unsigned* pairs = (unsigned*)bufA;
  unsigned* lin1  = (unsigned*)bufA;                       // (N+1)*64 uints
  unsigned* lin2  = (unsigned*)(bufA + (size_t)(N_NODES + 1) * 256);
  float* dinv = (float*)alloc((size_t)N_NODES * 4);
  float* tbuf = (float*)alloc((size_t)(N_NODES + 1) * 4);
  float* v3   = (float*)alloc(HC * 4);
  float* c3   = (float*)alloc(16);
  int* startA = (int*)alloc((size_t)N_NODES * 4);
  int* degA   = (int*)alloc((size_t)N_NODES * 4);
  // csr: padded spans (self-loop + edges + pad-to-8) <= E + 8*N
  int* csr    = (int*)alloc((size_t)(N_EDGES + 8 * N_NODES) * 4);  // 8.0 MB
  int* bbase  = (int*)alloc(NB * 4);
  int* bcur   = (int*)alloc(NB * 4);
  // zero zone: bcnt | total | ssum | cntg
  size_t zz_bytes = NB * 4 + 16 + G_C * 4 + G_C * 4;
  char* zz = alloc(zz_bytes);
  int*   bcnt = (int*)zz;
  int*   total= (int*)(zz + NB * 4);
  float* ssum = (float*)(zz + NB * 4 + 16);
  int*   cntg = (int*)(zz + NB * 4 + 16 + G_C * 4);

  hipMemsetAsync(zz, 0, zz_bytes, stream);

  k_bhist<<<NBLK_E, 256, 0, stream>>>(dstE, bcnt);
  k_prefix<<<1, 512, 0, stream>>>(bcnt, bbase, bcur);
  k_bin<<<NBLK_E, 256, 0, stream>>>(srcE, dstE, bcur, pairs);
  k_build<<<NB, 256, 0, stream>>>(pairs, bbase, bcur, total, startA, degA, dinv, csr);
  k_v3<<<1, 128, 0, stream>>>(W3, b3, Wl, v3, c3, lin1, lin2, tbuf);

  k_lin1<<<N_NODES / 4, 256, 0, stream>>>(x, W1, dinv, lin1);
  k_spmm<0><<<N_NODES / 4, 256, 0, stream>>>(lin1, dinv, startA, degA, csr, b1, v3, bufB);
  k_gemm<<<(N_NODES + GM - 1) / GM, 128, 0, stream>>>(bufB, W2, dinv, lin2);
  k_spmm<1><<<N_NODES / 4, 256, 0, stream>>>(lin2, dinv, startA, degA, csr, b2, v3, tbuf);
  k_spmv_pool<<<(N_NODES + 255) / 256, 256, 0, stream>>>(tbuf, dinv, startA, degA, csr,
                                                         c3, batch, ssum, cntg);
  k_out<<<(G_C + 255) / 256, 256, 0, stream>>>(ssum, cntg, bl, out);
}